// Round 4
// baseline (3591.155 us; speedup 1.0000x reference)
//
#include <hip/hip_runtime.h>

// HierarchicalResidualQuantizer on gfx950 — numpy-fp32-exact decision path.
// N=16384 tokens, D=256, L=8 levels, K=512 codes.
// Outputs (flat fp32 in d_out): q_out[16,256,32,32] @0, indices[16,32,32,8] @4194304,
// loss[16] @4325376, all_probs[16384,8,512] @4325392.  Total 71,434,256 floats.
// Scratch lives in the TAIL of the probs region (overwritten last by k_out2).

typedef _Float16 f16;
typedef _Float16 half8 __attribute__((ext_vector_type(8)));
typedef _Float16 half4v __attribute__((ext_vector_type(4)));
typedef float f32x4 __attribute__((ext_vector_type(4)));

#define LOGK 6.238324625039508f

#define OUT_IDX 4194304
#define OUT_LOSS 4325376
#define OUT_PROBS 4325392

#define SCR_FLOATS 5526784
// scratch offsets in floats
#define SF_ZH 0              // f16[16384*256]
#define SF_ZL 2097152        // f16[16384*256]
#define SF_WH 4194304        // f16[4096*256]
#define SF_WL 4718592        // f16[4096*256]
#define SF_B32 5242880       // float[4096]  fp32 pairwise ||w||^2 (numpy-exact)
#define SF_G32 5246976       // float[256]   fp32 global_sum (numpy-exact bits)
#define SF_G2D 5247232       // double[512]  2*g.w_k for next level (approx path)
#define SF_IDX 5248256       // int[16384*8]
#define SF_IDXL 5379328      // int[8*16384] level-major indices
#define SF_KL 5510400        // float[16384]

// ---------- numpy pairwise-128 block: 8 accumulators + fixed combine tree ----------
__device__ __forceinline__ float np_combine8(const float r[8]) {
    return __fadd_rn(__fadd_rn(__fadd_rn(r[0], r[1]), __fadd_rn(r[2], r[3])),
                     __fadd_rn(__fadd_rn(r[4], r[5]), __fadd_rn(r[6], r[7])));
}

__global__ void k_prep_z(const float* __restrict__ z, f16* __restrict__ zh, f16* __restrict__ zl) {
    int i = (blockIdx.x * 256 + threadIdx.x) * 4;
    float4 v = *(const float4*)(z + i);
    half4v h, l;
    float c0 = v.x, c1 = v.y, c2 = v.z, c3 = v.w;
    f16 h0 = (f16)c0, h1 = (f16)c1, h2 = (f16)c2, h3 = (f16)c3;
    h[0] = h0; h[1] = h1; h[2] = h2; h[3] = h3;
    l[0] = (f16)(c0 - (float)h0); l[1] = (f16)(c1 - (float)h1);
    l[2] = (f16)(c2 - (float)h2); l[3] = (f16)(c3 - (float)h3);
    *(half4v*)(zh + i) = h;
    *(half4v*)(zl + i) = l;
}

// fp16 hi/lo split of scaled codebooks (scale 2^(l+4), row norm ~16 at all levels)
__global__ void k_prep_w(const float* __restrict__ w, f16* __restrict__ wh, f16* __restrict__ wl) {
    int row = blockIdx.x * 4 + (threadIdx.x >> 6);
    int lane = threadIdx.x & 63;
    int lvl = row >> 9;
    float sc = (float)(1 << (lvl + 4));
    const float* wr = w + row * 256;
    int d0 = lane * 4;
    float4 v = *(const float4*)(wr + d0);
    half4v h, l;
    float s0 = v.x * sc, s1 = v.y * sc, s2 = v.z * sc, s3 = v.w * sc;
    f16 h0 = (f16)s0, h1 = (f16)s1, h2 = (f16)s2, h3 = (f16)s3;
    h[0] = h0; h[1] = h1; h[2] = h2; h[3] = h3;
    l[0] = (f16)(s0 - (float)h0); l[1] = (f16)(s1 - (float)h1);
    l[2] = (f16)(s2 - (float)h2); l[3] = (f16)(s3 - (float)h3);
    *(half4v*)(wh + row * 256 + d0) = h;
    *(half4v*)(wl + row * 256 + d0) = l;
}

// numpy-exact fp32 (Wl*Wl).sum(-1): pairwise256 = block128 + block128
__global__ void k_prep_b(const float* __restrict__ w, float* __restrict__ b32) {
    int row = blockIdx.x * 256 + threadIdx.x;   // 0..4095
    const float* wr = w + row * 256;
    float res[2];
    #pragma unroll
    for (int h = 0; h < 2; ++h) {
        const float* x = wr + h * 128;
        float r[8];
        #pragma unroll
        for (int j = 0; j < 8; ++j) r[j] = __fmul_rn(x[j], x[j]);
        for (int i = 8; i < 128; i += 8)
            #pragma unroll
            for (int j = 0; j < 8; ++j) r[j] = __fadd_rn(r[j], __fmul_rn(x[i + j], x[i + j]));
        res[h] = np_combine8(r);
    }
    b32[row] = __fadd_rn(res[0], res[1]);
}

__global__ void k_prep_misc(float* __restrict__ g32, double* __restrict__ G2, float* __restrict__ loss_out) {
    int t = threadIdx.x;
    g32[t] = 0.0f;
    G2[t] = 0.0; G2[t + 256] = 0.0;
    if (t < 16) loss_out[t] = 0.0f;
}

// Per-level: MFMA approx scores -> emulated fp32-quantized dist -> candidate
// pre-filter -> exact numpy-fp32 dist (sequential-FMA c) for candidates ->
// argmax (first-max-wins). KL from the quantized dist (matches fp32 ref).
__global__ __launch_bounds__(256) void k_level(
        const float* __restrict__ zf, const float* __restrict__ wf,
        const f16* __restrict__ zh, const f16* __restrict__ zl,
        const f16* __restrict__ wh, const f16* __restrict__ wl,
        const float* __restrict__ g32, const double* __restrict__ G2,
        const float* __restrict__ b32,
        int* __restrict__ idxws, int* __restrict__ idxL,
        float* __restrict__ klacc, int lvl) {
    __shared__ float bS[512];
    __shared__ double g2S[512];
    __shared__ float gS[256];
    __shared__ float pb[32][16];
    __shared__ float aS[32], mgS[32];
    __shared__ float DmaxW[4][32], DmaxS[32];
    __shared__ float seW[4][32], sdW[4][32];
    __shared__ unsigned short cand[32][256];
    __shared__ int ccnt[32];
    __shared__ int bidxS[32];

    const int tid = threadIdx.x;
    const int wave = tid >> 6, lane = tid & 63;
    const int quad = lane >> 4, lr = lane & 15;
    const int tok0 = blockIdx.x * 32;
    const int code0 = wave * 128;

    // stage
    gS[tid] = g32[tid];
    bS[tid] = b32[lvl * 512 + tid]; bS[tid + 256] = b32[lvl * 512 + tid + 256];
    g2S[tid] = G2[tid]; g2S[tid + 256] = G2[tid + 256];
    if (tid < 32) ccnt[tid] = 0;

    // Phase A: MFMA approx (3-term fp16 split, fp32 acc)
    const f16* za = zh + (tok0 + lr) * 256 + quad * 8;
    const f16* zb = zl + (tok0 + lr) * 256 + quad * 8;
    const f16* wa = wh + (lvl * 512 + code0 + lr) * 256 + quad * 8;
    const f16* wb = wl + (lvl * 512 + code0 + lr) * 256 + quad * 8;
    f32x4 acc[2][8];
    #pragma unroll
    for (int mt = 0; mt < 2; ++mt)
        #pragma unroll
        for (int nt = 0; nt < 8; ++nt)
            acc[mt][nt] = (f32x4){0.f, 0.f, 0.f, 0.f};
    for (int k0 = 0; k0 < 256; k0 += 32) {
        half8 ah0 = *(const half8*)(za + k0);
        half8 ah1 = *(const half8*)(za + 16 * 256 + k0);
        half8 al0 = *(const half8*)(zb + k0);
        half8 al1 = *(const half8*)(zb + 16 * 256 + k0);
        half8 bh[8], bl[8];
        #pragma unroll
        for (int nt = 0; nt < 8; ++nt) {
            bh[nt] = *(const half8*)(wa + nt * 16 * 256 + k0);
            bl[nt] = *(const half8*)(wb + nt * 16 * 256 + k0);
        }
        #pragma unroll
        for (int nt = 0; nt < 8; ++nt) {
            acc[0][nt] = __builtin_amdgcn_mfma_f32_16x16x32_f16(ah0, bh[nt], acc[0][nt], 0, 0, 0);
            acc[1][nt] = __builtin_amdgcn_mfma_f32_16x16x32_f16(ah1, bh[nt], acc[1][nt], 0, 0, 0);
            acc[0][nt] = __builtin_amdgcn_mfma_f32_16x16x32_f16(ah0, bl[nt], acc[0][nt], 0, 0, 0);
            acc[1][nt] = __builtin_amdgcn_mfma_f32_16x16x32_f16(ah1, bl[nt], acc[1][nt], 0, 0, 0);
            acc[0][nt] = __builtin_amdgcn_mfma_f32_16x16x32_f16(al0, bh[nt], acc[0][nt], 0, 0, 0);
            acc[1][nt] = __builtin_amdgcn_mfma_f32_16x16x32_f16(al1, bh[nt], acc[1][nt], 0, 0, 0);
        }
    }
    __syncthreads();

    // Phase B: a_n = numpy-pairwise fp32 sum of resid^2 (8 threads/token)
    {
        int t = tid >> 3, s = tid & 7;
        const float* zr = zf + (tok0 + t) * 256;
        #pragma unroll
        for (int h = 0; h < 2; ++h) {
            int base = h * 128 + s;
            float x0 = __fsub_rn(zr[base], gS[base]);
            float r = __fmul_rn(x0, x0);
            for (int i = 1; i < 16; ++i) {
                float xv = __fsub_rn(zr[base + i * 8], gS[base + i * 8]);
                r = __fadd_rn(r, __fmul_rn(xv, xv));
            }
            pb[t][h * 8 + s] = r;
        }
    }
    __syncthreads();
    if (tid < 32) {
        float r0[8], r1[8];
        #pragma unroll
        for (int j = 0; j < 8; ++j) { r0[j] = pb[tid][j]; r1[j] = pb[tid][8 + j]; }
        float a = __fadd_rn(np_combine8(r0), np_combine8(r1));
        aS[tid] = a;
        unsigned e = (__float_as_uint(a) >> 23) & 0xffu;
        float ulp = __uint_as_float((e - 23u) << 23);
        mgS[tid] = 2.5f * ulp + 1e-4f * sqrtf(a) / (float)(1 << lvl) + 1e-6f;
    }
    __syncthreads();

    // Phase C: emulated fp32-rounded dist, per-wave per-token max
    const double inv2 = 1.0 / (double)(1 << (lvl + 3));
    #pragma unroll
    for (int mt = 0; mt < 2; ++mt) {
        #pragma unroll
        for (int r = 0; r < 4; ++r) {
            int tl = mt * 16 + quad * 4 + r;
            float a = aS[tl];
            float m = -3.4e38f;
            #pragma unroll
            for (int nt = 0; nt < 8; ++nt) {
                int code = code0 + nt * 16 + lr;
                float c2 = (float)(inv2 * (double)acc[mt][nt][r] - g2S[code]);
                float D = -__fsub_rn(__fadd_rn(a, bS[code]), c2);
                m = fmaxf(m, D);
            }
            #pragma unroll
            for (int msk = 1; msk < 16; msk <<= 1) m = fmaxf(m, __shfl_xor(m, msk));
            if (lr == 0) DmaxW[wave][tl] = m;
        }
    }
    __syncthreads();
    if (tid < 32)
        DmaxS[tid] = fmaxf(fmaxf(DmaxW[0][tid], DmaxW[1][tid]),
                           fmaxf(DmaxW[2][tid], DmaxW[3][tid]));
    __syncthreads();

    // Phase C2: softmax stats (quantized dist) + candidate collection
    #pragma unroll
    for (int mt = 0; mt < 2; ++mt) {
        #pragma unroll
        for (int r = 0; r < 4; ++r) {
            int tl = mt * 16 + quad * 4 + r;
            float a = aS[tl], Dm = DmaxS[tl], mg = mgS[tl];
            float se = 0.f, sd = 0.f;
            #pragma unroll
            for (int nt = 0; nt < 8; ++nt) {
                int code = code0 + nt * 16 + lr;
                float c2 = (float)(inv2 * (double)acc[mt][nt][r] - g2S[code]);
                float D = -__fsub_rn(__fadd_rn(a, bS[code]), c2);
                float d = Dm - D;
                se += __expf(-d);
                sd += d;
                if (D >= Dm - mg) {
                    int pos = atomicAdd(&ccnt[tl], 1);
                    if (pos < 256) cand[tl][pos] = (unsigned short)code;
                }
            }
            #pragma unroll
            for (int msk = 1; msk < 16; msk <<= 1) {
                se += __shfl_xor(se, msk);
                sd += __shfl_xor(sd, msk);
            }
            if (lr == 0) { seW[wave][tl] = se; sdW[wave][tl] = sd; }
        }
    }
    __syncthreads();

    if (tid < 32) {
        float se = seW[0][tid] + seW[1][tid] + seW[2][tid] + seW[3][tid];
        float sd = sdW[0][tid] + sdW[1][tid] + sdW[2][tid] + sdW[3][tid];
        float kl = __logf(se) + sd * (1.0f / 512.0f) - LOGK;
        int n = tok0 + tid;
        float prev = (lvl == 0) ? 0.0f : klacc[n];
        klacc[n] = prev + 0.1f * kl;
    }

    // Phase E: exact numpy-fp32 dist for candidates (sequential-FMA c)
    {
        int t = tid >> 3, s = tid & 7;
        int n = tok0 + t;
        const float* zr = zf + n * 256;
        int cnt = ccnt[t]; if (cnt > 256) cnt = 256;
        float aT = aS[t];
        float bD = -3.4e38f; int bI = 0x7fffffff;
        for (int ci = s; ci < cnt; ci += 8) {
            int code = cand[t][ci];
            const float* wr = wf + (lvl * 512 + code) * 256;
            float c = 0.f;
            #pragma unroll 8
            for (int j = 0; j < 256; ++j)
                c = fmaf(__fsub_rn(zr[j], gS[j]), wr[j], c);
            float D = -__fsub_rn(__fadd_rn(aT, bS[code]), __fadd_rn(c, c));
            if (D > bD || (D == bD && code < bI)) { bD = D; bI = code; }
        }
        #pragma unroll
        for (int msk = 1; msk < 8; msk <<= 1) {
            float oD = __shfl_xor(bD, msk);
            int oI = __shfl_xor(bI, msk);
            if (oD > bD || (oD == bD && oI < bI)) { bD = oD; bI = oI; }
        }
        if (s == 0) bidxS[t] = bI;
    }
    __syncthreads();
    if (tid < 32) {
        int gi = bidxS[tid];
        int n = tok0 + tid;
        idxws[n * 8 + lvl] = gi;
        idxL[lvl * 16384 + n] = gi;
    }
}

// numpy-exact g update: S = q.sum(axis=0) is SEQUENTIAL over the 16384 rows
// (numpy pairwise applies only to contiguous inner-axis reductions);
// then g = fl32(g + S). One thread per dim. Then fp64 G2 = 2*g.w for next level.
__global__ __launch_bounds__(256) void k_gsum(const float* __restrict__ w,
        const int* __restrict__ idxL, float* __restrict__ g32,
        double* __restrict__ G2, int lvl) {
    __shared__ int cc[256];
    __shared__ float gf[256];
    int tid = threadIdx.x;
    float acc = 0.f;
    const float* wl = w + lvl * 131072;
    for (int base = 0; base < 16384; base += 256) {
        __syncthreads();
        cc[tid] = idxL[lvl * 16384 + base + tid];
        __syncthreads();
        #pragma unroll 8
        for (int i = 0; i < 256; ++i)
            acc = __fadd_rn(acc, wl[cc[i] * 256 + tid]);
    }
    float gv = __fadd_rn(g32[tid], acc);
    g32[tid] = gv;
    gf[tid] = gv;
    __syncthreads();
    const float* wn = w + (lvl + 1) * 131072;
    for (int k = tid; k < 512; k += 256) {
        const float* wr = wn + k * 256;
        double s = 0.0;
        for (int j = 0; j < 256; ++j) s = fma((double)gf[j], (double)wr[j], s);
        G2[k] = 2.0 * s;
    }
}

// Epilogue 1: q_out (transposed), indices (as float), per-image loss.
__global__ __launch_bounds__(256) void k_out1(const float* __restrict__ w,
        const float* __restrict__ b32, const int* __restrict__ idxws,
        const float* __restrict__ klacc, float* __restrict__ out) {
    __shared__ int lidx[64][8];
    int tid = threadIdx.x;
    int tok0 = blockIdx.x * 64;
    int b = tok0 >> 10, hw0 = tok0 & 1023;

    for (int s = tid; s < 512; s += 256) {
        int v = idxws[tok0 * 8 + s];
        lidx[s >> 3][s & 7] = v;
        out[OUT_IDX + tok0 * 8 + s] = (float)v;
    }
    __syncthreads();

    {
        int j = tid & 63, q = tid >> 6;
        int id[8];
        #pragma unroll
        for (int l = 0; l < 8; ++l) id[l] = lidx[j][l];
        for (int dd = 0; dd < 64; ++dd) {
            int d = q * 64 + dd;
            float s = 0.f;
            #pragma unroll
            for (int l = 0; l < 8; ++l) s += w[l * 131072 + id[l] * 256 + d];
            out[b * 262144 + d * 1024 + hw0 + j] = s;
        }
    }

    if (tid < 64) {
        int n = tok0 + tid;
        float lv = klacc[n];
        float nl = 0.f;
        #pragma unroll
        for (int jj = 0; jj < 7; ++jj) {
            float up = sqrtf(b32[jj * 512 + lidx[tid][jj]]);
            float lo = sqrtf(b32[(jj + 1) * 512 + lidx[tid][jj + 1]]);
            float ratio = 4.0f * (lo / up);
            float m = fmaxf(ratio, 1.0f) - 1.0f;
            nl += m * m;
        }
        lv += nl * (1.0f / 7.0f) * 0.1f;
        #pragma unroll
        for (int msk = 1; msk < 64; msk <<= 1) lv += __shfl_xor(lv, msk);
        if (tid == 0) atomicAdd(out + OUT_LOSS + b, lv * (1.0f / 1024.0f));
    }
}

// Epilogue 2: fill the ENTIRE probs region (one-hot), overwriting scratch tail.
__global__ __launch_bounds__(256) void k_out2(float* __restrict__ out) {
    __shared__ int lidx[16][8];
    int tid = threadIdx.x;
    int tok0 = blockIdx.x * 16;
    if (tid < 128) {
        int v = (int)out[OUT_IDX + tok0 * 8 + tid];
        lidx[tid >> 3][tid & 7] = v;
    }
    __syncthreads();
    float4* pb = (float4*)(out + OUT_PROBS) + (size_t)tok0 * 1024;
    for (int it = 0; it < 64; ++it) {
        int i = it * 256 + tid;
        int nl_ = i >> 10, l = (i >> 7) & 7, kg = i & 127;
        int rel = lidx[nl_][l] - kg * 4;
        float4 v;
        v.x = (rel == 0) ? 1.0f : 0.0f;
        v.y = (rel == 1) ? 1.0f : 0.0f;
        v.z = (rel == 2) ? 1.0f : 0.0f;
        v.w = (rel == 3) ? 1.0f : 0.0f;
        pb[i] = v;
    }
}

extern "C" void kernel_launch(void* const* d_in, const int* in_sizes, int n_in,
                              void* d_out, int out_size, void* d_ws, size_t ws_size,
                              hipStream_t stream) {
    const float* z = (const float*)d_in[0];
    const float* w = (const float*)d_in[1];
    float* out = (float*)d_out;

    float* sb = out + (out_size - SCR_FLOATS);
    f16* zh = (f16*)(sb + SF_ZH);
    f16* zl = (f16*)(sb + SF_ZL);
    f16* wh = (f16*)(sb + SF_WH);
    f16* wl = (f16*)(sb + SF_WL);
    float* b32 = (float*)(sb + SF_B32);
    float* g32 = (float*)(sb + SF_G32);
    double* G2 = (double*)(sb + SF_G2D);
    int* idxws = (int*)(sb + SF_IDX);
    int* idxL = (int*)(sb + SF_IDXL);
    float* klacc = (float*)(sb + SF_KL);

    k_prep_z<<<4096, 256, 0, stream>>>(z, zh, zl);
    k_prep_w<<<1024, 256, 0, stream>>>(w, wh, wl);
    k_prep_b<<<16, 256, 0, stream>>>(w, b32);
    k_prep_misc<<<1, 256, 0, stream>>>(g32, G2, out + OUT_LOSS);
    for (int l = 0; l < 8; ++l) {
        k_level<<<512, 256, 0, stream>>>(z, w, zh, zl, wh, wl, g32, G2, b32,
                                         idxws, idxL, klacc, l);
        if (l < 7) k_gsum<<<1, 256, 0, stream>>>(w, idxL, g32, G2, l);
    }
    k_out1<<<256, 256, 0, stream>>>(w, b32, idxws, klacc, out);
    k_out2<<<1024, 256, 0, stream>>>(out);
}

// Round 5
// 2903.958 us; speedup vs baseline: 1.2366x; 1.2366x over previous
//
#include <hip/hip_runtime.h>

// HierarchicalResidualQuantizer on gfx950 — numpy-fp32-exact decision path.
// N=16384 tokens, D=256, L=8 levels, K=512 codes.
// Outputs (flat fp32 in d_out): q_out[16,256,32,32] @0, indices[16,32,32,8] @4194304,
// loss[16] @4325376, all_probs[16384,8,512] @4325392.  Total 71,434,256 floats.
// Scratch lives in the TAIL of the probs region (overwritten last by k_out2).
//
// R5: k_gsum was 97% of runtime (7 x 500us, 1-block latency-serialized).
// Rewritten: 16 blocks x 16 dims (independent sequential chains), codes staged
// once in LDS, double-buffered VGPR prefetch ring (64+64 loads in flight).
// fp64 G2 phase split into k_g2 (parallel, wave-per-code-group).
// Summation ORDER per dim is bit-identical to R4 (validated numpy-exact).

typedef _Float16 f16;
typedef _Float16 half8 __attribute__((ext_vector_type(8)));
typedef _Float16 half4v __attribute__((ext_vector_type(4)));
typedef float f32x4 __attribute__((ext_vector_type(4)));

#define LOGK 6.238324625039508f

#define OUT_IDX 4194304
#define OUT_LOSS 4325376
#define OUT_PROBS 4325392

#define SCR_FLOATS 5526784
// scratch offsets in floats
#define SF_ZH 0              // f16[16384*256]
#define SF_ZL 2097152        // f16[16384*256]
#define SF_WH 4194304        // f16[4096*256]
#define SF_WL 4718592        // f16[4096*256]
#define SF_B32 5242880       // float[4096]  fp32 pairwise ||w||^2 (numpy-exact)
#define SF_G32 5246976       // float[256]   fp32 global_sum (numpy-exact bits)
#define SF_G2D 5247232       // double[512]  2*g.w_k for next level (approx path)
#define SF_IDX 5248256       // int[16384*8]
#define SF_IDXL 5379328      // int[8*16384] level-major indices
#define SF_KL 5510400        // float[16384]

// ---------- numpy pairwise-128 block: 8 accumulators + fixed combine tree ----------
__device__ __forceinline__ float np_combine8(const float r[8]) {
    return __fadd_rn(__fadd_rn(__fadd_rn(r[0], r[1]), __fadd_rn(r[2], r[3])),
                     __fadd_rn(__fadd_rn(r[4], r[5]), __fadd_rn(r[6], r[7])));
}

__global__ void k_prep_z(const float* __restrict__ z, f16* __restrict__ zh, f16* __restrict__ zl) {
    int i = (blockIdx.x * 256 + threadIdx.x) * 4;
    float4 v = *(const float4*)(z + i);
    half4v h, l;
    float c0 = v.x, c1 = v.y, c2 = v.z, c3 = v.w;
    f16 h0 = (f16)c0, h1 = (f16)c1, h2 = (f16)c2, h3 = (f16)c3;
    h[0] = h0; h[1] = h1; h[2] = h2; h[3] = h3;
    l[0] = (f16)(c0 - (float)h0); l[1] = (f16)(c1 - (float)h1);
    l[2] = (f16)(c2 - (float)h2); l[3] = (f16)(c3 - (float)h3);
    *(half4v*)(zh + i) = h;
    *(half4v*)(zl + i) = l;
}

// fp16 hi/lo split of scaled codebooks (scale 2^(l+4), row norm ~16 at all levels)
__global__ void k_prep_w(const float* __restrict__ w, f16* __restrict__ wh, f16* __restrict__ wl) {
    int row = blockIdx.x * 4 + (threadIdx.x >> 6);
    int lane = threadIdx.x & 63;
    int lvl = row >> 9;
    float sc = (float)(1 << (lvl + 4));
    const float* wr = w + row * 256;
    int d0 = lane * 4;
    float4 v = *(const float4*)(wr + d0);
    half4v h, l;
    float s0 = v.x * sc, s1 = v.y * sc, s2 = v.z * sc, s3 = v.w * sc;
    f16 h0 = (f16)s0, h1 = (f16)s1, h2 = (f16)s2, h3 = (f16)s3;
    h[0] = h0; h[1] = h1; h[2] = h2; h[3] = h3;
    l[0] = (f16)(s0 - (float)h0); l[1] = (f16)(s1 - (float)h1);
    l[2] = (f16)(s2 - (float)h2); l[3] = (f16)(s3 - (float)h3);
    *(half4v*)(wh + row * 256 + d0) = h;
    *(half4v*)(wl + row * 256 + d0) = l;
}

// numpy-exact fp32 (Wl*Wl).sum(-1): pairwise256 = block128 + block128
__global__ void k_prep_b(const float* __restrict__ w, float* __restrict__ b32) {
    int row = blockIdx.x * 256 + threadIdx.x;   // 0..4095
    const float* wr = w + row * 256;
    float res[2];
    #pragma unroll
    for (int h = 0; h < 2; ++h) {
        const float* x = wr + h * 128;
        float r[8];
        #pragma unroll
        for (int j = 0; j < 8; ++j) r[j] = __fmul_rn(x[j], x[j]);
        for (int i = 8; i < 128; i += 8)
            #pragma unroll
            for (int j = 0; j < 8; ++j) r[j] = __fadd_rn(r[j], __fmul_rn(x[i + j], x[i + j]));
        res[h] = np_combine8(r);
    }
    b32[row] = __fadd_rn(res[0], res[1]);
}

__global__ void k_prep_misc(float* __restrict__ g32, double* __restrict__ G2, float* __restrict__ loss_out) {
    int t = threadIdx.x;
    g32[t] = 0.0f;
    G2[t] = 0.0; G2[t + 256] = 0.0;
    if (t < 16) loss_out[t] = 0.0f;
}

// Per-level: MFMA approx scores -> emulated fp32-quantized dist -> candidate
// pre-filter -> exact numpy-fp32 dist (sequential-FMA c) for candidates ->
// argmax (first-max-wins). KL from the quantized dist (matches fp32 ref).
__global__ __launch_bounds__(256) void k_level(
        const float* __restrict__ zf, const float* __restrict__ wf,
        const f16* __restrict__ zh, const f16* __restrict__ zl,
        const f16* __restrict__ wh, const f16* __restrict__ wl,
        const float* __restrict__ g32, const double* __restrict__ G2,
        const float* __restrict__ b32,
        int* __restrict__ idxws, int* __restrict__ idxL,
        float* __restrict__ klacc, int lvl) {
    __shared__ float bS[512];
    __shared__ double g2S[512];
    __shared__ float gS[256];
    __shared__ float pb[32][16];
    __shared__ float aS[32], mgS[32];
    __shared__ float DmaxW[4][32], DmaxS[32];
    __shared__ float seW[4][32], sdW[4][32];
    __shared__ unsigned short cand[32][256];
    __shared__ int ccnt[32];
    __shared__ int bidxS[32];

    const int tid = threadIdx.x;
    const int wave = tid >> 6, lane = tid & 63;
    const int quad = lane >> 4, lr = lane & 15;
    const int tok0 = blockIdx.x * 32;
    const int code0 = wave * 128;

    // stage
    gS[tid] = g32[tid];
    bS[tid] = b32[lvl * 512 + tid]; bS[tid + 256] = b32[lvl * 512 + tid + 256];
    g2S[tid] = G2[tid]; g2S[tid + 256] = G2[tid + 256];
    if (tid < 32) ccnt[tid] = 0;

    // Phase A: MFMA approx (3-term fp16 split, fp32 acc)
    const f16* za = zh + (tok0 + lr) * 256 + quad * 8;
    const f16* zb = zl + (tok0 + lr) * 256 + quad * 8;
    const f16* wa = wh + (lvl * 512 + code0 + lr) * 256 + quad * 8;
    const f16* wb = wl + (lvl * 512 + code0 + lr) * 256 + quad * 8;
    f32x4 acc[2][8];
    #pragma unroll
    for (int mt = 0; mt < 2; ++mt)
        #pragma unroll
        for (int nt = 0; nt < 8; ++nt)
            acc[mt][nt] = (f32x4){0.f, 0.f, 0.f, 0.f};
    for (int k0 = 0; k0 < 256; k0 += 32) {
        half8 ah0 = *(const half8*)(za + k0);
        half8 ah1 = *(const half8*)(za + 16 * 256 + k0);
        half8 al0 = *(const half8*)(zb + k0);
        half8 al1 = *(const half8*)(zb + 16 * 256 + k0);
        half8 bh[8], bl[8];
        #pragma unroll
        for (int nt = 0; nt < 8; ++nt) {
            bh[nt] = *(const half8*)(wa + nt * 16 * 256 + k0);
            bl[nt] = *(const half8*)(wb + nt * 16 * 256 + k0);
        }
        #pragma unroll
        for (int nt = 0; nt < 8; ++nt) {
            acc[0][nt] = __builtin_amdgcn_mfma_f32_16x16x32_f16(ah0, bh[nt], acc[0][nt], 0, 0, 0);
            acc[1][nt] = __builtin_amdgcn_mfma_f32_16x16x32_f16(ah1, bh[nt], acc[1][nt], 0, 0, 0);
            acc[0][nt] = __builtin_amdgcn_mfma_f32_16x16x32_f16(ah0, bl[nt], acc[0][nt], 0, 0, 0);
            acc[1][nt] = __builtin_amdgcn_mfma_f32_16x16x32_f16(ah1, bl[nt], acc[1][nt], 0, 0, 0);
            acc[0][nt] = __builtin_amdgcn_mfma_f32_16x16x32_f16(al0, bh[nt], acc[0][nt], 0, 0, 0);
            acc[1][nt] = __builtin_amdgcn_mfma_f32_16x16x32_f16(al1, bh[nt], acc[1][nt], 0, 0, 0);
        }
    }
    __syncthreads();

    // Phase B: a_n = numpy-pairwise fp32 sum of resid^2 (8 threads/token)
    {
        int t = tid >> 3, s = tid & 7;
        const float* zr = zf + (tok0 + t) * 256;
        #pragma unroll
        for (int h = 0; h < 2; ++h) {
            int base = h * 128 + s;
            float x0 = __fsub_rn(zr[base], gS[base]);
            float r = __fmul_rn(x0, x0);
            for (int i = 1; i < 16; ++i) {
                float xv = __fsub_rn(zr[base + i * 8], gS[base + i * 8]);
                r = __fadd_rn(r, __fmul_rn(xv, xv));
            }
            pb[t][h * 8 + s] = r;
        }
    }
    __syncthreads();
    if (tid < 32) {
        float r0[8], r1[8];
        #pragma unroll
        for (int j = 0; j < 8; ++j) { r0[j] = pb[tid][j]; r1[j] = pb[tid][8 + j]; }
        float a = __fadd_rn(np_combine8(r0), np_combine8(r1));
        aS[tid] = a;
        unsigned e = (__float_as_uint(a) >> 23) & 0xffu;
        float ulp = __uint_as_float((e - 23u) << 23);
        mgS[tid] = 2.5f * ulp + 1e-4f * sqrtf(a) / (float)(1 << lvl) + 1e-6f;
    }
    __syncthreads();

    // Phase C: emulated fp32-rounded dist, per-wave per-token max
    const double inv2 = 1.0 / (double)(1 << (lvl + 3));
    #pragma unroll
    for (int mt = 0; mt < 2; ++mt) {
        #pragma unroll
        for (int r = 0; r < 4; ++r) {
            int tl = mt * 16 + quad * 4 + r;
            float a = aS[tl];
            float m = -3.4e38f;
            #pragma unroll
            for (int nt = 0; nt < 8; ++nt) {
                int code = code0 + nt * 16 + lr;
                float c2 = (float)(inv2 * (double)acc[mt][nt][r] - g2S[code]);
                float D = -__fsub_rn(__fadd_rn(a, bS[code]), c2);
                m = fmaxf(m, D);
            }
            #pragma unroll
            for (int msk = 1; msk < 16; msk <<= 1) m = fmaxf(m, __shfl_xor(m, msk));
            if (lr == 0) DmaxW[wave][tl] = m;
        }
    }
    __syncthreads();
    if (tid < 32)
        DmaxS[tid] = fmaxf(fmaxf(DmaxW[0][tid], DmaxW[1][tid]),
                           fmaxf(DmaxW[2][tid], DmaxW[3][tid]));
    __syncthreads();

    // Phase C2: softmax stats (quantized dist) + candidate collection
    #pragma unroll
    for (int mt = 0; mt < 2; ++mt) {
        #pragma unroll
        for (int r = 0; r < 4; ++r) {
            int tl = mt * 16 + quad * 4 + r;
            float a = aS[tl], Dm = DmaxS[tl], mg = mgS[tl];
            float se = 0.f, sd = 0.f;
            #pragma unroll
            for (int nt = 0; nt < 8; ++nt) {
                int code = code0 + nt * 16 + lr;
                float c2 = (float)(inv2 * (double)acc[mt][nt][r] - g2S[code]);
                float D = -__fsub_rn(__fadd_rn(a, bS[code]), c2);
                float d = Dm - D;
                se += __expf(-d);
                sd += d;
                if (D >= Dm - mg) {
                    int pos = atomicAdd(&ccnt[tl], 1);
                    if (pos < 256) cand[tl][pos] = (unsigned short)code;
                }
            }
            #pragma unroll
            for (int msk = 1; msk < 16; msk <<= 1) {
                se += __shfl_xor(se, msk);
                sd += __shfl_xor(sd, msk);
            }
            if (lr == 0) { seW[wave][tl] = se; sdW[wave][tl] = sd; }
        }
    }
    __syncthreads();

    if (tid < 32) {
        float se = seW[0][tid] + seW[1][tid] + seW[2][tid] + seW[3][tid];
        float sd = sdW[0][tid] + sdW[1][tid] + sdW[2][tid] + sdW[3][tid];
        float kl = __logf(se) + sd * (1.0f / 512.0f) - LOGK;
        int n = tok0 + tid;
        float prev = (lvl == 0) ? 0.0f : klacc[n];
        klacc[n] = prev + 0.1f * kl;
    }

    // Phase E: exact numpy-fp32 dist for candidates (sequential-FMA c)
    {
        int t = tid >> 3, s = tid & 7;
        int n = tok0 + t;
        const float* zr = zf + n * 256;
        int cnt = ccnt[t]; if (cnt > 256) cnt = 256;
        float aT = aS[t];
        float bD = -3.4e38f; int bI = 0x7fffffff;
        for (int ci = s; ci < cnt; ci += 8) {
            int code = cand[t][ci];
            const float* wr = wf + (lvl * 512 + code) * 256;
            float c = 0.f;
            #pragma unroll 8
            for (int j = 0; j < 256; ++j)
                c = fmaf(__fsub_rn(zr[j], gS[j]), wr[j], c);
            float D = -__fsub_rn(__fadd_rn(aT, bS[code]), __fadd_rn(c, c));
            if (D > bD || (D == bD && code < bI)) { bD = D; bI = code; }
        }
        #pragma unroll
        for (int msk = 1; msk < 8; msk <<= 1) {
            float oD = __shfl_xor(bD, msk);
            int oI = __shfl_xor(bI, msk);
            if (oD > bD || (oD == bD && oI < bI)) { bD = oD; bI = oI; }
        }
        if (s == 0) bidxS[t] = bI;
    }
    __syncthreads();
    if (tid < 32) {
        int gi = bidxS[tid];
        int n = tok0 + tid;
        idxws[n * 8 + lvl] = gi;
        idxL[lvl * 16384 + n] = gi;
    }
}

// numpy-exact g update, parallel over dims: 16 blocks x 16 dims, each dim an
// independent sequential fp32 chain in EXACT token order (bit-identical to the
// validated R4 order: acc=0; acc=fl(acc+w[code_i][d]) ascending i; g=fl(g+acc)).
// Codes staged once in LDS; double-buffered 64-deep VGPR prefetch ring keeps
// ~64-128 loads in flight to cover L2 latency.
#define GS_BATCH 64
__global__ __launch_bounds__(64) void k_gsum(const float* __restrict__ w,
        const int* __restrict__ idxL, float* __restrict__ g32, int lvl) {
    __shared__ int codes[16384];
    const int tid = threadIdx.x;
    {
        const int4* src = (const int4*)(idxL + lvl * 16384);
        int4* dst = (int4*)codes;
        for (int i = tid; i < 4096; i += 64) dst[i] = src[i];
    }
    __syncthreads();
    if (tid < 16) {
        const int d = blockIdx.x * 16 + tid;
        const float* wl = w + lvl * 131072 + d;
        float A[GS_BATCH], B[GS_BATCH];
        float acc = 0.f;
        #pragma unroll
        for (int j = 0; j < GS_BATCH; ++j) A[j] = wl[codes[j] << 8];
        for (int base = 0; base < 16384; base += 2 * GS_BATCH) {
            #pragma unroll
            for (int j = 0; j < GS_BATCH; ++j) B[j] = wl[codes[base + GS_BATCH + j] << 8];
            #pragma unroll
            for (int j = 0; j < GS_BATCH; ++j) acc = __fadd_rn(acc, A[j]);
            if (base + 2 * GS_BATCH < 16384) {
                #pragma unroll
                for (int j = 0; j < GS_BATCH; ++j) A[j] = wl[codes[base + 2 * GS_BATCH + j] << 8];
            }
            #pragma unroll
            for (int j = 0; j < GS_BATCH; ++j) acc = __fadd_rn(acc, B[j]);
        }
        g32[d] = __fadd_rn(g32[d], acc);
    }
}

// fp64 G2[k] = 2 * g . W_{l+1}[k,:] — parallel, wave per 16 codes.
__global__ __launch_bounds__(256) void k_g2(const float* __restrict__ w,
        const float* __restrict__ g32, double* __restrict__ G2, int lvl) {
    __shared__ float gf[256];
    int tid = threadIdx.x;
    gf[tid] = g32[tid];
    __syncthreads();
    int wave = tid >> 6, lane = tid & 63;
    int code0 = blockIdx.x * 64 + wave * 16;
    const float* wn = w + (lvl + 1) * 131072;
    int d0 = lane * 4;
    double gd0 = (double)gf[d0], gd1 = (double)gf[d0 + 1];
    double gd2 = (double)gf[d0 + 2], gd3 = (double)gf[d0 + 3];
    for (int k = code0; k < code0 + 16; ++k) {
        float4 v = *(const float4*)(wn + k * 256 + d0);
        double p = gd0 * (double)v.x + gd1 * (double)v.y
                 + gd2 * (double)v.z + gd3 * (double)v.w;
        #pragma unroll
        for (int msk = 1; msk < 64; msk <<= 1) p += __shfl_xor(p, msk);
        if (lane == 0) G2[k] = 2.0 * p;
    }
}

// Epilogue 1: q_out (transposed), indices (as float), per-image loss.
__global__ __launch_bounds__(256) void k_out1(const float* __restrict__ w,
        const float* __restrict__ b32, const int* __restrict__ idxws,
        const float* __restrict__ klacc, float* __restrict__ out) {
    __shared__ int lidx[64][8];
    int tid = threadIdx.x;
    int tok0 = blockIdx.x * 64;
    int b = tok0 >> 10, hw0 = tok0 & 1023;

    for (int s = tid; s < 512; s += 256) {
        int v = idxws[tok0 * 8 + s];
        lidx[s >> 3][s & 7] = v;
        out[OUT_IDX + tok0 * 8 + s] = (float)v;
    }
    __syncthreads();

    {
        int j = tid & 63, q = tid >> 6;
        int id[8];
        #pragma unroll
        for (int l = 0; l < 8; ++l) id[l] = lidx[j][l];
        for (int dd = 0; dd < 64; ++dd) {
            int d = q * 64 + dd;
            float s = 0.f;
            #pragma unroll
            for (int l = 0; l < 8; ++l) s += w[l * 131072 + id[l] * 256 + d];
            out[b * 262144 + d * 1024 + hw0 + j] = s;
        }
    }

    if (tid < 64) {
        int n = tok0 + tid;
        float lv = klacc[n];
        float nl = 0.f;
        #pragma unroll
        for (int jj = 0; jj < 7; ++jj) {
            float up = sqrtf(b32[jj * 512 + lidx[tid][jj]]);
            float lo = sqrtf(b32[(jj + 1) * 512 + lidx[tid][jj + 1]]);
            float ratio = 4.0f * (lo / up);
            float m = fmaxf(ratio, 1.0f) - 1.0f;
            nl += m * m;
        }
        lv += nl * (1.0f / 7.0f) * 0.1f;
        #pragma unroll
        for (int msk = 1; msk < 64; msk <<= 1) lv += __shfl_xor(lv, msk);
        if (tid == 0) atomicAdd(out + OUT_LOSS + b, lv * (1.0f / 1024.0f));
    }
}

// Epilogue 2: fill the ENTIRE probs region (one-hot), overwriting scratch tail.
__global__ __launch_bounds__(256) void k_out2(float* __restrict__ out) {
    __shared__ int lidx[16][8];
    int tid = threadIdx.x;
    int tok0 = blockIdx.x * 16;
    if (tid < 128) {
        int v = (int)out[OUT_IDX + tok0 * 8 + tid];
        lidx[tid >> 3][tid & 7] = v;
    }
    __syncthreads();
    float4* pb = (float4*)(out + OUT_PROBS) + (size_t)tok0 * 1024;
    for (int it = 0; it < 64; ++it) {
        int i = it * 256 + tid;
        int nl_ = i >> 10, l = (i >> 7) & 7, kg = i & 127;
        int rel = lidx[nl_][l] - kg * 4;
        float4 v;
        v.x = (rel == 0) ? 1.0f : 0.0f;
        v.y = (rel == 1) ? 1.0f : 0.0f;
        v.z = (rel == 2) ? 1.0f : 0.0f;
        v.w = (rel == 3) ? 1.0f : 0.0f;
        pb[i] = v;
    }
}

extern "C" void kernel_launch(void* const* d_in, const int* in_sizes, int n_in,
                              void* d_out, int out_size, void* d_ws, size_t ws_size,
                              hipStream_t stream) {
    const float* z = (const float*)d_in[0];
    const float* w = (const float*)d_in[1];
    float* out = (float*)d_out;

    float* sb = out + (out_size - SCR_FLOATS);
    f16* zh = (f16*)(sb + SF_ZH);
    f16* zl = (f16*)(sb + SF_ZL);
    f16* wh = (f16*)(sb + SF_WH);
    f16* wl = (f16*)(sb + SF_WL);
    float* b32 = (float*)(sb + SF_B32);
    float* g32 = (float*)(sb + SF_G32);
    double* G2 = (double*)(sb + SF_G2D);
    int* idxws = (int*)(sb + SF_IDX);
    int* idxL = (int*)(sb + SF_IDXL);
    float* klacc = (float*)(sb + SF_KL);

    k_prep_z<<<4096, 256, 0, stream>>>(z, zh, zl);
    k_prep_w<<<1024, 256, 0, stream>>>(w, wh, wl);
    k_prep_b<<<16, 256, 0, stream>>>(w, b32);
    k_prep_misc<<<1, 256, 0, stream>>>(g32, G2, out + OUT_LOSS);
    for (int l = 0; l < 8; ++l) {
        k_level<<<512, 256, 0, stream>>>(z, w, zh, zl, wh, wl, g32, G2, b32,
                                         idxws, idxL, klacc, l);
        if (l < 7) {
            k_gsum<<<16, 64, 0, stream>>>(w, idxL, g32, l);
            k_g2<<<8, 256, 0, stream>>>(w, g32, G2, l);
        }
    }
    k_out1<<<256, 256, 0, stream>>>(w, b32, idxws, klacc, out);
    k_out2<<<1024, 256, 0, stream>>>(out);
}

// Round 6
// 1947.202 us; speedup vs baseline: 1.8443x; 1.4913x over previous
//
#include <hip/hip_runtime.h>

// HierarchicalResidualQuantizer on gfx950 — numpy-fp32-exact decision path.
// N=16384 tokens, D=256, L=8 levels, K=512 codes.
// Outputs (flat fp32 in d_out): q_out[16,256,32,32] @0, indices[16,32,32,8] @4194304,
// loss[16] @4325376, all_probs[16384,8,512] @4325392.  Total 71,434,256 floats.
// Scratch lives in the TAIL of the probs region (overwritten last by k_out2).
//
// R6: k_gsum v3 — all-LDS chain. R5's version (286us) serialized on
// ds_read->addr->global-gather dependent chains (~42 cyc/elem). Now the 32KB
// column block w[512][16] is staged into LDS once; the 16384-long sequential
// fp32 chain (order bit-identical to validated R4: acc=0, token-ascending,
// g=fl(g+acc)) reads only LDS: broadcast b128 codes + conflict-free b32 gather.

typedef _Float16 f16;
typedef _Float16 half8 __attribute__((ext_vector_type(8)));
typedef _Float16 half4v __attribute__((ext_vector_type(4)));
typedef float f32x4 __attribute__((ext_vector_type(4)));

#define LOGK 6.238324625039508f

#define OUT_IDX 4194304
#define OUT_LOSS 4325376
#define OUT_PROBS 4325392

#define SCR_FLOATS 5526784
// scratch offsets in floats
#define SF_ZH 0              // f16[16384*256]
#define SF_ZL 2097152        // f16[16384*256]
#define SF_WH 4194304        // f16[4096*256]
#define SF_WL 4718592        // f16[4096*256]
#define SF_B32 5242880       // float[4096]  fp32 pairwise ||w||^2 (numpy-exact)
#define SF_G32 5246976       // float[256]   fp32 global_sum (numpy-exact bits)
#define SF_G2D 5247232       // double[512]  2*g.w_k for next level (approx path)
#define SF_IDX 5248256       // int[16384*8]
#define SF_IDXL 5379328      // int[8*16384] level-major indices
#define SF_KL 5510400        // float[16384]

// ---------- numpy pairwise-128 block: 8 accumulators + fixed combine tree ----------
__device__ __forceinline__ float np_combine8(const float r[8]) {
    return __fadd_rn(__fadd_rn(__fadd_rn(r[0], r[1]), __fadd_rn(r[2], r[3])),
                     __fadd_rn(__fadd_rn(r[4], r[5]), __fadd_rn(r[6], r[7])));
}

__global__ void k_prep_z(const float* __restrict__ z, f16* __restrict__ zh, f16* __restrict__ zl) {
    int i = (blockIdx.x * 256 + threadIdx.x) * 4;
    float4 v = *(const float4*)(z + i);
    half4v h, l;
    float c0 = v.x, c1 = v.y, c2 = v.z, c3 = v.w;
    f16 h0 = (f16)c0, h1 = (f16)c1, h2 = (f16)c2, h3 = (f16)c3;
    h[0] = h0; h[1] = h1; h[2] = h2; h[3] = h3;
    l[0] = (f16)(c0 - (float)h0); l[1] = (f16)(c1 - (float)h1);
    l[2] = (f16)(c2 - (float)h2); l[3] = (f16)(c3 - (float)h3);
    *(half4v*)(zh + i) = h;
    *(half4v*)(zl + i) = l;
}

// fp16 hi/lo split of scaled codebooks (scale 2^(l+4), row norm ~16 at all levels)
__global__ void k_prep_w(const float* __restrict__ w, f16* __restrict__ wh, f16* __restrict__ wl) {
    int row = blockIdx.x * 4 + (threadIdx.x >> 6);
    int lane = threadIdx.x & 63;
    int lvl = row >> 9;
    float sc = (float)(1 << (lvl + 4));
    const float* wr = w + row * 256;
    int d0 = lane * 4;
    float4 v = *(const float4*)(wr + d0);
    half4v h, l;
    float s0 = v.x * sc, s1 = v.y * sc, s2 = v.z * sc, s3 = v.w * sc;
    f16 h0 = (f16)s0, h1 = (f16)s1, h2 = (f16)s2, h3 = (f16)s3;
    h[0] = h0; h[1] = h1; h[2] = h2; h[3] = h3;
    l[0] = (f16)(s0 - (float)h0); l[1] = (f16)(s1 - (float)h1);
    l[2] = (f16)(s2 - (float)h2); l[3] = (f16)(s3 - (float)h3);
    *(half4v*)(wh + row * 256 + d0) = h;
    *(half4v*)(wl + row * 256 + d0) = l;
}

// numpy-exact fp32 (Wl*Wl).sum(-1): pairwise256 = block128 + block128
__global__ void k_prep_b(const float* __restrict__ w, float* __restrict__ b32) {
    int row = blockIdx.x * 256 + threadIdx.x;   // 0..4095
    const float* wr = w + row * 256;
    float res[2];
    #pragma unroll
    for (int h = 0; h < 2; ++h) {
        const float* x = wr + h * 128;
        float r[8];
        #pragma unroll
        for (int j = 0; j < 8; ++j) r[j] = __fmul_rn(x[j], x[j]);
        for (int i = 8; i < 128; i += 8)
            #pragma unroll
            for (int j = 0; j < 8; ++j) r[j] = __fadd_rn(r[j], __fmul_rn(x[i + j], x[i + j]));
        res[h] = np_combine8(r);
    }
    b32[row] = __fadd_rn(res[0], res[1]);
}

__global__ void k_prep_misc(float* __restrict__ g32, double* __restrict__ G2, float* __restrict__ loss_out) {
    int t = threadIdx.x;
    g32[t] = 0.0f;
    G2[t] = 0.0; G2[t + 256] = 0.0;
    if (t < 16) loss_out[t] = 0.0f;
}

// Per-level: MFMA approx scores -> emulated fp32-quantized dist -> candidate
// pre-filter -> exact numpy-fp32 dist (sequential-FMA c) for candidates ->
// argmax (first-max-wins). KL from the quantized dist (matches fp32 ref).
__global__ __launch_bounds__(256) void k_level(
        const float* __restrict__ zf, const float* __restrict__ wf,
        const f16* __restrict__ zh, const f16* __restrict__ zl,
        const f16* __restrict__ wh, const f16* __restrict__ wl,
        const float* __restrict__ g32, const double* __restrict__ G2,
        const float* __restrict__ b32,
        int* __restrict__ idxws, int* __restrict__ idxL,
        float* __restrict__ klacc, int lvl) {
    __shared__ float bS[512];
    __shared__ double g2S[512];
    __shared__ float gS[256];
    __shared__ float pb[32][16];
    __shared__ float aS[32], mgS[32];
    __shared__ float DmaxW[4][32], DmaxS[32];
    __shared__ float seW[4][32], sdW[4][32];
    __shared__ unsigned short cand[32][256];
    __shared__ int ccnt[32];
    __shared__ int bidxS[32];

    const int tid = threadIdx.x;
    const int wave = tid >> 6, lane = tid & 63;
    const int quad = lane >> 4, lr = lane & 15;
    const int tok0 = blockIdx.x * 32;
    const int code0 = wave * 128;

    // stage
    gS[tid] = g32[tid];
    bS[tid] = b32[lvl * 512 + tid]; bS[tid + 256] = b32[lvl * 512 + tid + 256];
    g2S[tid] = G2[tid]; g2S[tid + 256] = G2[tid + 256];
    if (tid < 32) ccnt[tid] = 0;

    // Phase A: MFMA approx (3-term fp16 split, fp32 acc)
    const f16* za = zh + (tok0 + lr) * 256 + quad * 8;
    const f16* zb = zl + (tok0 + lr) * 256 + quad * 8;
    const f16* wa = wh + (lvl * 512 + code0 + lr) * 256 + quad * 8;
    const f16* wb = wl + (lvl * 512 + code0 + lr) * 256 + quad * 8;
    f32x4 acc[2][8];
    #pragma unroll
    for (int mt = 0; mt < 2; ++mt)
        #pragma unroll
        for (int nt = 0; nt < 8; ++nt)
            acc[mt][nt] = (f32x4){0.f, 0.f, 0.f, 0.f};
    for (int k0 = 0; k0 < 256; k0 += 32) {
        half8 ah0 = *(const half8*)(za + k0);
        half8 ah1 = *(const half8*)(za + 16 * 256 + k0);
        half8 al0 = *(const half8*)(zb + k0);
        half8 al1 = *(const half8*)(zb + 16 * 256 + k0);
        half8 bh[8], bl[8];
        #pragma unroll
        for (int nt = 0; nt < 8; ++nt) {
            bh[nt] = *(const half8*)(wa + nt * 16 * 256 + k0);
            bl[nt] = *(const half8*)(wb + nt * 16 * 256 + k0);
        }
        #pragma unroll
        for (int nt = 0; nt < 8; ++nt) {
            acc[0][nt] = __builtin_amdgcn_mfma_f32_16x16x32_f16(ah0, bh[nt], acc[0][nt], 0, 0, 0);
            acc[1][nt] = __builtin_amdgcn_mfma_f32_16x16x32_f16(ah1, bh[nt], acc[1][nt], 0, 0, 0);
            acc[0][nt] = __builtin_amdgcn_mfma_f32_16x16x32_f16(ah0, bl[nt], acc[0][nt], 0, 0, 0);
            acc[1][nt] = __builtin_amdgcn_mfma_f32_16x16x32_f16(ah1, bl[nt], acc[1][nt], 0, 0, 0);
            acc[0][nt] = __builtin_amdgcn_mfma_f32_16x16x32_f16(al0, bh[nt], acc[0][nt], 0, 0, 0);
            acc[1][nt] = __builtin_amdgcn_mfma_f32_16x16x32_f16(al1, bh[nt], acc[1][nt], 0, 0, 0);
        }
    }
    __syncthreads();

    // Phase B: a_n = numpy-pairwise fp32 sum of resid^2 (8 threads/token)
    {
        int t = tid >> 3, s = tid & 7;
        const float* zr = zf + (tok0 + t) * 256;
        #pragma unroll
        for (int h = 0; h < 2; ++h) {
            int base = h * 128 + s;
            float x0 = __fsub_rn(zr[base], gS[base]);
            float r = __fmul_rn(x0, x0);
            for (int i = 1; i < 16; ++i) {
                float xv = __fsub_rn(zr[base + i * 8], gS[base + i * 8]);
                r = __fadd_rn(r, __fmul_rn(xv, xv));
            }
            pb[t][h * 8 + s] = r;
        }
    }
    __syncthreads();
    if (tid < 32) {
        float r0[8], r1[8];
        #pragma unroll
        for (int j = 0; j < 8; ++j) { r0[j] = pb[tid][j]; r1[j] = pb[tid][8 + j]; }
        float a = __fadd_rn(np_combine8(r0), np_combine8(r1));
        aS[tid] = a;
        unsigned e = (__float_as_uint(a) >> 23) & 0xffu;
        float ulp = __uint_as_float((e - 23u) << 23);
        mgS[tid] = 2.5f * ulp + 1e-4f * sqrtf(a) / (float)(1 << lvl) + 1e-6f;
    }
    __syncthreads();

    // Phase C: emulated fp32-rounded dist, per-wave per-token max
    const double inv2 = 1.0 / (double)(1 << (lvl + 3));
    #pragma unroll
    for (int mt = 0; mt < 2; ++mt) {
        #pragma unroll
        for (int r = 0; r < 4; ++r) {
            int tl = mt * 16 + quad * 4 + r;
            float a = aS[tl];
            float m = -3.4e38f;
            #pragma unroll
            for (int nt = 0; nt < 8; ++nt) {
                int code = code0 + nt * 16 + lr;
                float c2 = (float)(inv2 * (double)acc[mt][nt][r] - g2S[code]);
                float D = -__fsub_rn(__fadd_rn(a, bS[code]), c2);
                m = fmaxf(m, D);
            }
            #pragma unroll
            for (int msk = 1; msk < 16; msk <<= 1) m = fmaxf(m, __shfl_xor(m, msk));
            if (lr == 0) DmaxW[wave][tl] = m;
        }
    }
    __syncthreads();
    if (tid < 32)
        DmaxS[tid] = fmaxf(fmaxf(DmaxW[0][tid], DmaxW[1][tid]),
                           fmaxf(DmaxW[2][tid], DmaxW[3][tid]));
    __syncthreads();

    // Phase C2: softmax stats (quantized dist) + candidate collection
    #pragma unroll
    for (int mt = 0; mt < 2; ++mt) {
        #pragma unroll
        for (int r = 0; r < 4; ++r) {
            int tl = mt * 16 + quad * 4 + r;
            float a = aS[tl], Dm = DmaxS[tl], mg = mgS[tl];
            float se = 0.f, sd = 0.f;
            #pragma unroll
            for (int nt = 0; nt < 8; ++nt) {
                int code = code0 + nt * 16 + lr;
                float c2 = (float)(inv2 * (double)acc[mt][nt][r] - g2S[code]);
                float D = -__fsub_rn(__fadd_rn(a, bS[code]), c2);
                float d = Dm - D;
                se += __expf(-d);
                sd += d;
                if (D >= Dm - mg) {
                    int pos = atomicAdd(&ccnt[tl], 1);
                    if (pos < 256) cand[tl][pos] = (unsigned short)code;
                }
            }
            #pragma unroll
            for (int msk = 1; msk < 16; msk <<= 1) {
                se += __shfl_xor(se, msk);
                sd += __shfl_xor(sd, msk);
            }
            if (lr == 0) { seW[wave][tl] = se; sdW[wave][tl] = sd; }
        }
    }
    __syncthreads();

    if (tid < 32) {
        float se = seW[0][tid] + seW[1][tid] + seW[2][tid] + seW[3][tid];
        float sd = sdW[0][tid] + sdW[1][tid] + sdW[2][tid] + sdW[3][tid];
        float kl = __logf(se) + sd * (1.0f / 512.0f) - LOGK;
        int n = tok0 + tid;
        float prev = (lvl == 0) ? 0.0f : klacc[n];
        klacc[n] = prev + 0.1f * kl;
    }

    // Phase E: exact numpy-fp32 dist for candidates (sequential-FMA c)
    {
        int t = tid >> 3, s = tid & 7;
        int n = tok0 + t;
        const float* zr = zf + n * 256;
        int cnt = ccnt[t]; if (cnt > 256) cnt = 256;
        float aT = aS[t];
        float bD = -3.4e38f; int bI = 0x7fffffff;
        for (int ci = s; ci < cnt; ci += 8) {
            int code = cand[t][ci];
            const float* wr = wf + (lvl * 512 + code) * 256;
            float c = 0.f;
            #pragma unroll 8
            for (int j = 0; j < 256; ++j)
                c = fmaf(__fsub_rn(zr[j], gS[j]), wr[j], c);
            float D = -__fsub_rn(__fadd_rn(aT, bS[code]), __fadd_rn(c, c));
            if (D > bD || (D == bD && code < bI)) { bD = D; bI = code; }
        }
        #pragma unroll
        for (int msk = 1; msk < 8; msk <<= 1) {
            float oD = __shfl_xor(bD, msk);
            int oI = __shfl_xor(bI, msk);
            if (oD > bD || (oD == bD && oI < bI)) { bD = oD; bI = oI; }
        }
        if (s == 0) bidxS[t] = bI;
    }
    __syncthreads();
    if (tid < 32) {
        int gi = bidxS[tid];
        int n = tok0 + tid;
        idxws[n * 8 + lvl] = gi;
        idxL[lvl * 16384 + n] = gi;
    }
}

// numpy-exact g update v3, all-LDS: 16 blocks x 16 dims. Per block, stage the
// 512x16 column slice of W_l (32 KB) and the 16384 codes (64 KB) into LDS,
// then 16 lanes run independent sequential fp32 chains in EXACT token order
// (bit-identical to validated R4: acc=0; acc=fl(acc+w[code_i][d]); g=fl(g+acc)).
// Chain reads: broadcast ds_read_b128 for codes (4 codes/read) + conflict-free
// ds_read_b32 gather (16 lanes -> 16 distinct banks).
__global__ __launch_bounds__(256) void k_gsum(const float* __restrict__ w,
        const int* __restrict__ idxL, float* __restrict__ g32, int lvl) {
    __shared__ int codes[16384];
    __shared__ float wcol[8192];    // [row][dim] 512 x 16
    const int tid = threadIdx.x;
    const int dimbase = blockIdx.x * 16;
    {
        const int4* src = (const int4*)(idxL + lvl * 16384);
        int4* dst = (int4*)codes;
        #pragma unroll
        for (int i = 0; i < 16; ++i) dst[tid + i * 256] = src[tid + i * 256];
        const float* wb = w + lvl * 131072 + dimbase;
        #pragma unroll
        for (int i = 0; i < 32; ++i) {
            int idx = tid + i * 256;             // 0..8191
            wcol[idx] = wb[(idx >> 4) * 256 + (idx & 15)];
        }
    }
    __syncthreads();
    if (tid < 16) {
        const int d = tid;
        float acc = 0.f;
        for (int base = 0; base < 16384; base += 64) {
            int4 cc[16];
            #pragma unroll
            for (int j = 0; j < 16; ++j) cc[j] = *(const int4*)(codes + base + j * 4);
            float v[64];
            #pragma unroll
            for (int j = 0; j < 16; ++j) {
                v[4 * j + 0] = wcol[(cc[j].x << 4) + d];
                v[4 * j + 1] = wcol[(cc[j].y << 4) + d];
                v[4 * j + 2] = wcol[(cc[j].z << 4) + d];
                v[4 * j + 3] = wcol[(cc[j].w << 4) + d];
            }
            #pragma unroll
            for (int j = 0; j < 64; ++j) acc = __fadd_rn(acc, v[j]);
        }
        g32[dimbase + d] = __fadd_rn(g32[dimbase + d], acc);
    }
}

// fp64 G2[k] = 2 * g . W_{l+1}[k,:] — parallel, wave per 16 codes.
__global__ __launch_bounds__(256) void k_g2(const float* __restrict__ w,
        const float* __restrict__ g32, double* __restrict__ G2, int lvl) {
    __shared__ float gf[256];
    int tid = threadIdx.x;
    gf[tid] = g32[tid];
    __syncthreads();
    int wave = tid >> 6, lane = tid & 63;
    int code0 = blockIdx.x * 64 + wave * 16;
    const float* wn = w + (lvl + 1) * 131072;
    int d0 = lane * 4;
    double gd0 = (double)gf[d0], gd1 = (double)gf[d0 + 1];
    double gd2 = (double)gf[d0 + 2], gd3 = (double)gf[d0 + 3];
    for (int k = code0; k < code0 + 16; ++k) {
        float4 v = *(const float4*)(wn + k * 256 + d0);
        double p = gd0 * (double)v.x + gd1 * (double)v.y
                 + gd2 * (double)v.z + gd3 * (double)v.w;
        #pragma unroll
        for (int msk = 1; msk < 64; msk <<= 1) p += __shfl_xor(p, msk);
        if (lane == 0) G2[k] = 2.0 * p;
    }
}

// Epilogue 1: q_out (transposed), indices (as float), per-image loss.
__global__ __launch_bounds__(256) void k_out1(const float* __restrict__ w,
        const float* __restrict__ b32, const int* __restrict__ idxws,
        const float* __restrict__ klacc, float* __restrict__ out) {
    __shared__ int lidx[64][8];
    int tid = threadIdx.x;
    int tok0 = blockIdx.x * 64;
    int b = tok0 >> 10, hw0 = tok0 & 1023;

    for (int s = tid; s < 512; s += 256) {
        int v = idxws[tok0 * 8 + s];
        lidx[s >> 3][s & 7] = v;
        out[OUT_IDX + tok0 * 8 + s] = (float)v;
    }
    __syncthreads();

    {
        int j = tid & 63, q = tid >> 6;
        int id[8];
        #pragma unroll
        for (int l = 0; l < 8; ++l) id[l] = lidx[j][l];
        for (int dd = 0; dd < 64; ++dd) {
            int d = q * 64 + dd;
            float s = 0.f;
            #pragma unroll
            for (int l = 0; l < 8; ++l) s += w[l * 131072 + id[l] * 256 + d];
            out[b * 262144 + d * 1024 + hw0 + j] = s;
        }
    }

    if (tid < 64) {
        int n = tok0 + tid;
        float lv = klacc[n];
        float nl = 0.f;
        #pragma unroll
        for (int jj = 0; jj < 7; ++jj) {
            float up = sqrtf(b32[jj * 512 + lidx[tid][jj]]);
            float lo = sqrtf(b32[(jj + 1) * 512 + lidx[tid][jj + 1]]);
            float ratio = 4.0f * (lo / up);
            float m = fmaxf(ratio, 1.0f) - 1.0f;
            nl += m * m;
        }
        lv += nl * (1.0f / 7.0f) * 0.1f;
        #pragma unroll
        for (int msk = 1; msk < 64; msk <<= 1) lv += __shfl_xor(lv, msk);
        if (tid == 0) atomicAdd(out + OUT_LOSS + b, lv * (1.0f / 1024.0f));
    }
}

// Epilogue 2: fill the ENTIRE probs region (one-hot), overwriting scratch tail.
__global__ __launch_bounds__(256) void k_out2(float* __restrict__ out) {
    __shared__ int lidx[16][8];
    int tid = threadIdx.x;
    int tok0 = blockIdx.x * 16;
    if (tid < 128) {
        int v = (int)out[OUT_IDX + tok0 * 8 + tid];
        lidx[tid >> 3][tid & 7] = v;
    }
    __syncthreads();
    float4* pb = (float4*)(out + OUT_PROBS) + (size_t)tok0 * 1024;
    for (int it = 0; it < 64; ++it) {
        int i = it * 256 + tid;
        int nl_ = i >> 10, l = (i >> 7) & 7, kg = i & 127;
        int rel = lidx[nl_][l] - kg * 4;
        float4 v;
        v.x = (rel == 0) ? 1.0f : 0.0f;
        v.y = (rel == 1) ? 1.0f : 0.0f;
        v.z = (rel == 2) ? 1.0f : 0.0f;
        v.w = (rel == 3) ? 1.0f : 0.0f;
        pb[i] = v;
    }
}

extern "C" void kernel_launch(void* const* d_in, const int* in_sizes, int n_in,
                              void* d_out, int out_size, void* d_ws, size_t ws_size,
                              hipStream_t stream) {
    const float* z = (const float*)d_in[0];
    const float* w = (const float*)d_in[1];
    float* out = (float*)d_out;

    float* sb = out + (out_size - SCR_FLOATS);
    f16* zh = (f16*)(sb + SF_ZH);
    f16* zl = (f16*)(sb + SF_ZL);
    f16* wh = (f16*)(sb + SF_WH);
    f16* wl = (f16*)(sb + SF_WL);
    float* b32 = (float*)(sb + SF_B32);
    float* g32 = (float*)(sb + SF_G32);
    double* G2 = (double*)(sb + SF_G2D);
    int* idxws = (int*)(sb + SF_IDX);
    int* idxL = (int*)(sb + SF_IDXL);
    float* klacc = (float*)(sb + SF_KL);

    k_prep_z<<<4096, 256, 0, stream>>>(z, zh, zl);
    k_prep_w<<<1024, 256, 0, stream>>>(w, wh, wl);
    k_prep_b<<<16, 256, 0, stream>>>(w, b32);
    k_prep_misc<<<1, 256, 0, stream>>>(g32, G2, out + OUT_LOSS);
    for (int l = 0; l < 8; ++l) {
        k_level<<<512, 256, 0, stream>>>(z, w, zh, zl, wh, wl, g32, G2, b32,
                                         idxws, idxL, klacc, l);
        if (l < 7) {
            k_gsum<<<16, 256, 0, stream>>>(w, idxL, g32, l);
            k_g2<<<8, 256, 0, stream>>>(w, g32, G2, l);
        }
    }
    k_out1<<<256, 256, 0, stream>>>(w, b32, idxws, klacc, out);
    k_out2<<<1024, 256, 0, stream>>>(out);
}

// Round 7
// 1518.084 us; speedup vs baseline: 2.3656x; 1.2827x over previous
//
#include <hip/hip_runtime.h>

// HierarchicalResidualQuantizer on gfx950 — numpy-fp32-exact decision path.
// N=16384 tokens, D=256, L=8 levels, K=512 codes.
// Outputs (flat fp32 in d_out): q_out[16,256,32,32] @0, indices[16,32,32,8] @4194304,
// loss[16] @4325376, all_probs[16384,8,512] @4325392.  Total 71,434,256 floats.
// Scratch lives in the TAIL of the probs region (overwritten last by k_out2).
//
// R7: k_gsum v4 — producer/consumer ping-pong. R6 (150us) made the single
// consumer wave issue both DS gathers and the dependent add chain, with
// lgkmcnt(0) serialization (~9cyc/elem). Now 3 producer waves gather
// w[code][d] into double-buffered vals[dim][token] LDS while the consumer
// wave streams ds_read_b128 + the sequential fp32 chain (~4.3 cyc/elem).
// Order stays bit-identical to validated R4 (token-ascending, acc=0,
// g=fl(g+acc)); staged values are exact fp32 copies.

typedef _Float16 f16;
typedef _Float16 half8 __attribute__((ext_vector_type(8)));
typedef _Float16 half4v __attribute__((ext_vector_type(4)));
typedef float f32x4 __attribute__((ext_vector_type(4)));

#define LOGK 6.238324625039508f

#define OUT_IDX 4194304
#define OUT_LOSS 4325376
#define OUT_PROBS 4325392

#define SCR_FLOATS 5526784
// scratch offsets in floats
#define SF_ZH 0              // f16[16384*256]
#define SF_ZL 2097152        // f16[16384*256]
#define SF_WH 4194304        // f16[4096*256]
#define SF_WL 4718592        // f16[4096*256]
#define SF_B32 5242880       // float[4096]  fp32 pairwise ||w||^2 (numpy-exact)
#define SF_G32 5246976       // float[256]   fp32 global_sum (numpy-exact bits)
#define SF_G2D 5247232       // double[512]  2*g.w_k for next level (approx path)
#define SF_IDX 5248256       // int[16384*8]
#define SF_IDXL 5379328      // int[8*16384] level-major indices
#define SF_KL 5510400        // float[16384]

// ---------- numpy pairwise-128 block: 8 accumulators + fixed combine tree ----------
__device__ __forceinline__ float np_combine8(const float r[8]) {
    return __fadd_rn(__fadd_rn(__fadd_rn(r[0], r[1]), __fadd_rn(r[2], r[3])),
                     __fadd_rn(__fadd_rn(r[4], r[5]), __fadd_rn(r[6], r[7])));
}

__global__ void k_prep_z(const float* __restrict__ z, f16* __restrict__ zh, f16* __restrict__ zl) {
    int i = (blockIdx.x * 256 + threadIdx.x) * 4;
    float4 v = *(const float4*)(z + i);
    half4v h, l;
    float c0 = v.x, c1 = v.y, c2 = v.z, c3 = v.w;
    f16 h0 = (f16)c0, h1 = (f16)c1, h2 = (f16)c2, h3 = (f16)c3;
    h[0] = h0; h[1] = h1; h[2] = h2; h[3] = h3;
    l[0] = (f16)(c0 - (float)h0); l[1] = (f16)(c1 - (float)h1);
    l[2] = (f16)(c2 - (float)h2); l[3] = (f16)(c3 - (float)h3);
    *(half4v*)(zh + i) = h;
    *(half4v*)(zl + i) = l;
}

// fp16 hi/lo split of scaled codebooks (scale 2^(l+4), row norm ~16 at all levels)
__global__ void k_prep_w(const float* __restrict__ w, f16* __restrict__ wh, f16* __restrict__ wl) {
    int row = blockIdx.x * 4 + (threadIdx.x >> 6);
    int lane = threadIdx.x & 63;
    int lvl = row >> 9;
    float sc = (float)(1 << (lvl + 4));
    const float* wr = w + row * 256;
    int d0 = lane * 4;
    float4 v = *(const float4*)(wr + d0);
    half4v h, l;
    float s0 = v.x * sc, s1 = v.y * sc, s2 = v.z * sc, s3 = v.w * sc;
    f16 h0 = (f16)s0, h1 = (f16)s1, h2 = (f16)s2, h3 = (f16)s3;
    h[0] = h0; h[1] = h1; h[2] = h2; h[3] = h3;
    l[0] = (f16)(s0 - (float)h0); l[1] = (f16)(s1 - (float)h1);
    l[2] = (f16)(s2 - (float)h2); l[3] = (f16)(s3 - (float)h3);
    *(half4v*)(wh + row * 256 + d0) = h;
    *(half4v*)(wl + row * 256 + d0) = l;
}

// numpy-exact fp32 (Wl*Wl).sum(-1): pairwise256 = block128 + block128
__global__ void k_prep_b(const float* __restrict__ w, float* __restrict__ b32) {
    int row = blockIdx.x * 256 + threadIdx.x;   // 0..4095
    const float* wr = w + row * 256;
    float res[2];
    #pragma unroll
    for (int h = 0; h < 2; ++h) {
        const float* x = wr + h * 128;
        float r[8];
        #pragma unroll
        for (int j = 0; j < 8; ++j) r[j] = __fmul_rn(x[j], x[j]);
        for (int i = 8; i < 128; i += 8)
            #pragma unroll
            for (int j = 0; j < 8; ++j) r[j] = __fadd_rn(r[j], __fmul_rn(x[i + j], x[i + j]));
        res[h] = np_combine8(r);
    }
    b32[row] = __fadd_rn(res[0], res[1]);
}

__global__ void k_prep_misc(float* __restrict__ g32, double* __restrict__ G2, float* __restrict__ loss_out) {
    int t = threadIdx.x;
    g32[t] = 0.0f;
    G2[t] = 0.0; G2[t + 256] = 0.0;
    if (t < 16) loss_out[t] = 0.0f;
}

// Per-level: MFMA approx scores -> emulated fp32-quantized dist -> candidate
// pre-filter -> exact numpy-fp32 dist (sequential-FMA c) for candidates ->
// argmax (first-max-wins). KL from the quantized dist (matches fp32 ref).
__global__ __launch_bounds__(256) void k_level(
        const float* __restrict__ zf, const float* __restrict__ wf,
        const f16* __restrict__ zh, const f16* __restrict__ zl,
        const f16* __restrict__ wh, const f16* __restrict__ wl,
        const float* __restrict__ g32, const double* __restrict__ G2,
        const float* __restrict__ b32,
        int* __restrict__ idxws, int* __restrict__ idxL,
        float* __restrict__ klacc, int lvl) {
    __shared__ float bS[512];
    __shared__ double g2S[512];
    __shared__ float gS[256];
    __shared__ float pb[32][16];
    __shared__ float aS[32], mgS[32];
    __shared__ float DmaxW[4][32], DmaxS[32];
    __shared__ float seW[4][32], sdW[4][32];
    __shared__ unsigned short cand[32][256];
    __shared__ int ccnt[32];
    __shared__ int bidxS[32];

    const int tid = threadIdx.x;
    const int wave = tid >> 6, lane = tid & 63;
    const int quad = lane >> 4, lr = lane & 15;
    const int tok0 = blockIdx.x * 32;
    const int code0 = wave * 128;

    // stage
    gS[tid] = g32[tid];
    bS[tid] = b32[lvl * 512 + tid]; bS[tid + 256] = b32[lvl * 512 + tid + 256];
    g2S[tid] = G2[tid]; g2S[tid + 256] = G2[tid + 256];
    if (tid < 32) ccnt[tid] = 0;

    // Phase A: MFMA approx (3-term fp16 split, fp32 acc)
    const f16* za = zh + (tok0 + lr) * 256 + quad * 8;
    const f16* zb = zl + (tok0 + lr) * 256 + quad * 8;
    const f16* wa = wh + (lvl * 512 + code0 + lr) * 256 + quad * 8;
    const f16* wb = wl + (lvl * 512 + code0 + lr) * 256 + quad * 8;
    f32x4 acc[2][8];
    #pragma unroll
    for (int mt = 0; mt < 2; ++mt)
        #pragma unroll
        for (int nt = 0; nt < 8; ++nt)
            acc[mt][nt] = (f32x4){0.f, 0.f, 0.f, 0.f};
    for (int k0 = 0; k0 < 256; k0 += 32) {
        half8 ah0 = *(const half8*)(za + k0);
        half8 ah1 = *(const half8*)(za + 16 * 256 + k0);
        half8 al0 = *(const half8*)(zb + k0);
        half8 al1 = *(const half8*)(zb + 16 * 256 + k0);
        half8 bh[8], bl[8];
        #pragma unroll
        for (int nt = 0; nt < 8; ++nt) {
            bh[nt] = *(const half8*)(wa + nt * 16 * 256 + k0);
            bl[nt] = *(const half8*)(wb + nt * 16 * 256 + k0);
        }
        #pragma unroll
        for (int nt = 0; nt < 8; ++nt) {
            acc[0][nt] = __builtin_amdgcn_mfma_f32_16x16x32_f16(ah0, bh[nt], acc[0][nt], 0, 0, 0);
            acc[1][nt] = __builtin_amdgcn_mfma_f32_16x16x32_f16(ah1, bh[nt], acc[1][nt], 0, 0, 0);
            acc[0][nt] = __builtin_amdgcn_mfma_f32_16x16x32_f16(ah0, bl[nt], acc[0][nt], 0, 0, 0);
            acc[1][nt] = __builtin_amdgcn_mfma_f32_16x16x32_f16(ah1, bl[nt], acc[1][nt], 0, 0, 0);
            acc[0][nt] = __builtin_amdgcn_mfma_f32_16x16x32_f16(al0, bh[nt], acc[0][nt], 0, 0, 0);
            acc[1][nt] = __builtin_amdgcn_mfma_f32_16x16x32_f16(al1, bh[nt], acc[1][nt], 0, 0, 0);
        }
    }
    __syncthreads();

    // Phase B: a_n = numpy-pairwise fp32 sum of resid^2 (8 threads/token)
    {
        int t = tid >> 3, s = tid & 7;
        const float* zr = zf + (tok0 + t) * 256;
        #pragma unroll
        for (int h = 0; h < 2; ++h) {
            int base = h * 128 + s;
            float x0 = __fsub_rn(zr[base], gS[base]);
            float r = __fmul_rn(x0, x0);
            for (int i = 1; i < 16; ++i) {
                float xv = __fsub_rn(zr[base + i * 8], gS[base + i * 8]);
                r = __fadd_rn(r, __fmul_rn(xv, xv));
            }
            pb[t][h * 8 + s] = r;
        }
    }
    __syncthreads();
    if (tid < 32) {
        float r0[8], r1[8];
        #pragma unroll
        for (int j = 0; j < 8; ++j) { r0[j] = pb[tid][j]; r1[j] = pb[tid][8 + j]; }
        float a = __fadd_rn(np_combine8(r0), np_combine8(r1));
        aS[tid] = a;
        unsigned e = (__float_as_uint(a) >> 23) & 0xffu;
        float ulp = __uint_as_float((e - 23u) << 23);
        mgS[tid] = 2.5f * ulp + 1e-4f * sqrtf(a) / (float)(1 << lvl) + 1e-6f;
    }
    __syncthreads();

    // Phase C: emulated fp32-rounded dist, per-wave per-token max
    const double inv2 = 1.0 / (double)(1 << (lvl + 3));
    #pragma unroll
    for (int mt = 0; mt < 2; ++mt) {
        #pragma unroll
        for (int r = 0; r < 4; ++r) {
            int tl = mt * 16 + quad * 4 + r;
            float a = aS[tl];
            float m = -3.4e38f;
            #pragma unroll
            for (int nt = 0; nt < 8; ++nt) {
                int code = code0 + nt * 16 + lr;
                float c2 = (float)(inv2 * (double)acc[mt][nt][r] - g2S[code]);
                float D = -__fsub_rn(__fadd_rn(a, bS[code]), c2);
                m = fmaxf(m, D);
            }
            #pragma unroll
            for (int msk = 1; msk < 16; msk <<= 1) m = fmaxf(m, __shfl_xor(m, msk));
            if (lr == 0) DmaxW[wave][tl] = m;
        }
    }
    __syncthreads();
    if (tid < 32)
        DmaxS[tid] = fmaxf(fmaxf(DmaxW[0][tid], DmaxW[1][tid]),
                           fmaxf(DmaxW[2][tid], DmaxW[3][tid]));
    __syncthreads();

    // Phase C2: softmax stats (quantized dist) + candidate collection
    #pragma unroll
    for (int mt = 0; mt < 2; ++mt) {
        #pragma unroll
        for (int r = 0; r < 4; ++r) {
            int tl = mt * 16 + quad * 4 + r;
            float a = aS[tl], Dm = DmaxS[tl], mg = mgS[tl];
            float se = 0.f, sd = 0.f;
            #pragma unroll
            for (int nt = 0; nt < 8; ++nt) {
                int code = code0 + nt * 16 + lr;
                float c2 = (float)(inv2 * (double)acc[mt][nt][r] - g2S[code]);
                float D = -__fsub_rn(__fadd_rn(a, bS[code]), c2);
                float d = Dm - D;
                se += __expf(-d);
                sd += d;
                if (D >= Dm - mg) {
                    int pos = atomicAdd(&ccnt[tl], 1);
                    if (pos < 256) cand[tl][pos] = (unsigned short)code;
                }
            }
            #pragma unroll
            for (int msk = 1; msk < 16; msk <<= 1) {
                se += __shfl_xor(se, msk);
                sd += __shfl_xor(sd, msk);
            }
            if (lr == 0) { seW[wave][tl] = se; sdW[wave][tl] = sd; }
        }
    }
    __syncthreads();

    if (tid < 32) {
        float se = seW[0][tid] + seW[1][tid] + seW[2][tid] + seW[3][tid];
        float sd = sdW[0][tid] + sdW[1][tid] + sdW[2][tid] + sdW[3][tid];
        float kl = __logf(se) + sd * (1.0f / 512.0f) - LOGK;
        int n = tok0 + tid;
        float prev = (lvl == 0) ? 0.0f : klacc[n];
        klacc[n] = prev + 0.1f * kl;
    }

    // Phase E: exact numpy-fp32 dist for candidates (sequential-FMA c)
    {
        int t = tid >> 3, s = tid & 7;
        int n = tok0 + t;
        const float* zr = zf + n * 256;
        int cnt = ccnt[t]; if (cnt > 256) cnt = 256;
        float aT = aS[t];
        float bD = -3.4e38f; int bI = 0x7fffffff;
        for (int ci = s; ci < cnt; ci += 8) {
            int code = cand[t][ci];
            const float* wr = wf + (lvl * 512 + code) * 256;
            float c = 0.f;
            #pragma unroll 8
            for (int j = 0; j < 256; ++j)
                c = fmaf(__fsub_rn(zr[j], gS[j]), wr[j], c);
            float D = -__fsub_rn(__fadd_rn(aT, bS[code]), __fadd_rn(c, c));
            if (D > bD || (D == bD && code < bI)) { bD = D; bI = code; }
        }
        #pragma unroll
        for (int msk = 1; msk < 8; msk <<= 1) {
            float oD = __shfl_xor(bD, msk);
            int oI = __shfl_xor(bI, msk);
            if (oD > bD || (oD == bD && oI < bI)) { bD = oD; bI = oI; }
        }
        if (s == 0) bidxS[t] = bI;
    }
    __syncthreads();
    if (tid < 32) {
        int gi = bidxS[tid];
        int n = tok0 + tid;
        idxws[n * 8 + lvl] = gi;
        idxL[lvl * 16384 + n] = gi;
    }
}

// numpy-exact g update v4: producer/consumer ping-pong. 32 blocks x 8 dims.
// wcol[512][13-stride] staged once (16B rows padded to randomize banks).
// 3 producer waves gather chunk ch+1 (512 tokens) into vals[buf][dim][tok]
// while consumer wave (lanes 56-63 of wave 3) runs the sequential fp32 chain
// over chunk ch via ds_read_b128 (4 tok/instr, conflict-free: 516-stride).
// Chain order bit-identical to validated R4: acc=0, token-ascending fl-adds,
// g=fl(g+acc). Staged values are exact fp32 copies of w[lvl][code][d].
__global__ __launch_bounds__(256) void k_gsum(const float* __restrict__ w,
        const int* __restrict__ idxL, float* __restrict__ g32, int lvl) {
    __shared__ float wcol[512 * 13];       // [code][dim(8) pad to 13]
    __shared__ float vals[2][8][516];      // [buf][dim][token-in-chunk]
    const int tid = threadIdx.x;
    const int d0 = blockIdx.x * 8;
    {   // stage the 512x8 column slice
        const float* wb = w + lvl * 131072 + d0;
        for (int i = tid; i < 4096; i += 256)
            wcol[(i >> 3) * 13 + (i & 7)] = wb[(i >> 3) * 256 + (i & 7)];
    }
    const int* __restrict__ codes = idxL + lvl * 16384;
    const bool producer = (tid < 192);
    // fill chunk 0
    if (producer) {
        for (int k = tid; k < 512; k += 192) {
            int c = codes[k] * 13;
            float v0 = wcol[c], v1 = wcol[c + 1], v2 = wcol[c + 2], v3 = wcol[c + 3];
            float v4 = wcol[c + 4], v5 = wcol[c + 5], v6 = wcol[c + 6], v7 = wcol[c + 7];
            vals[0][0][k] = v0; vals[0][1][k] = v1; vals[0][2][k] = v2; vals[0][3][k] = v3;
            vals[0][4][k] = v4; vals[0][5][k] = v5; vals[0][6][k] = v6; vals[0][7][k] = v7;
        }
    }
    __syncthreads();
    float acc = 0.f;
    for (int ch = 0; ch < 32; ++ch) {
        const int cb = ch & 1, nb = cb ^ 1;
        if (producer) {
            if (ch < 31) {
                int base = (ch + 1) << 9;
                for (int k = tid; k < 512; k += 192) {
                    int c = codes[base + k] * 13;
                    float v0 = wcol[c], v1 = wcol[c + 1], v2 = wcol[c + 2], v3 = wcol[c + 3];
                    float v4 = wcol[c + 4], v5 = wcol[c + 5], v6 = wcol[c + 6], v7 = wcol[c + 7];
                    vals[nb][0][k] = v0; vals[nb][1][k] = v1; vals[nb][2][k] = v2; vals[nb][3][k] = v3;
                    vals[nb][4][k] = v4; vals[nb][5][k] = v5; vals[nb][6][k] = v6; vals[nb][7][k] = v7;
                }
            }
        } else if (tid >= 248) {
            const float* vp = &vals[cb][tid - 248][0];
            #pragma unroll 8
            for (int i = 0; i < 512; i += 4) {
                float4 v = *(const float4*)(vp + i);
                acc = __fadd_rn(acc, v.x);
                acc = __fadd_rn(acc, v.y);
                acc = __fadd_rn(acc, v.z);
                acc = __fadd_rn(acc, v.w);
            }
        }
        __syncthreads();
    }
    if (tid >= 248) {
        int d = d0 + tid - 248;
        g32[d] = __fadd_rn(g32[d], acc);
    }
}

// fp64 G2[k] = 2 * g . W_{l+1}[k,:] — parallel, wave per 16 codes.
__global__ __launch_bounds__(256) void k_g2(const float* __restrict__ w,
        const float* __restrict__ g32, double* __restrict__ G2, int lvl) {
    __shared__ float gf[256];
    int tid = threadIdx.x;
    gf[tid] = g32[tid];
    __syncthreads();
    int wave = tid >> 6, lane = tid & 63;
    int code0 = blockIdx.x * 64 + wave * 16;
    const float* wn = w + (lvl + 1) * 131072;
    int d0 = lane * 4;
    double gd0 = (double)gf[d0], gd1 = (double)gf[d0 + 1];
    double gd2 = (double)gf[d0 + 2], gd3 = (double)gf[d0 + 3];
    for (int k = code0; k < code0 + 16; ++k) {
        float4 v = *(const float4*)(wn + k * 256 + d0);
        double p = gd0 * (double)v.x + gd1 * (double)v.y
                 + gd2 * (double)v.z + gd3 * (double)v.w;
        #pragma unroll
        for (int msk = 1; msk < 64; msk <<= 1) p += __shfl_xor(p, msk);
        if (lane == 0) G2[k] = 2.0 * p;
    }
}

// Epilogue 1: q_out (transposed), indices (as float), per-image loss.
__global__ __launch_bounds__(256) void k_out1(const float* __restrict__ w,
        const float* __restrict__ b32, const int* __restrict__ idxws,
        const float* __restrict__ klacc, float* __restrict__ out) {
    __shared__ int lidx[64][8];
    int tid = threadIdx.x;
    int tok0 = blockIdx.x * 64;
    int b = tok0 >> 10, hw0 = tok0 & 1023;

    for (int s = tid; s < 512; s += 256) {
        int v = idxws[tok0 * 8 + s];
        lidx[s >> 3][s & 7] = v;
        out[OUT_IDX + tok0 * 8 + s] = (float)v;
    }
    __syncthreads();

    {
        int j = tid & 63, q = tid >> 6;
        int id[8];
        #pragma unroll
        for (int l = 0; l < 8; ++l) id[l] = lidx[j][l];
        for (int dd = 0; dd < 64; ++dd) {
            int d = q * 64 + dd;
            float s = 0.f;
            #pragma unroll
            for (int l = 0; l < 8; ++l) s += w[l * 131072 + id[l] * 256 + d];
            out[b * 262144 + d * 1024 + hw0 + j] = s;
        }
    }

    if (tid < 64) {
        int n = tok0 + tid;
        float lv = klacc[n];
        float nl = 0.f;
        #pragma unroll
        for (int jj = 0; jj < 7; ++jj) {
            float up = sqrtf(b32[jj * 512 + lidx[tid][jj]]);
            float lo = sqrtf(b32[(jj + 1) * 512 + lidx[tid][jj + 1]]);
            float ratio = 4.0f * (lo / up);
            float m = fmaxf(ratio, 1.0f) - 1.0f;
            nl += m * m;
        }
        lv += nl * (1.0f / 7.0f) * 0.1f;
        #pragma unroll
        for (int msk = 1; msk < 64; msk <<= 1) lv += __shfl_xor(lv, msk);
        if (tid == 0) atomicAdd(out + OUT_LOSS + b, lv * (1.0f / 1024.0f));
    }
}

// Epilogue 2: fill the ENTIRE probs region (one-hot), overwriting scratch tail.
__global__ __launch_bounds__(256) void k_out2(float* __restrict__ out) {
    __shared__ int lidx[16][8];
    int tid = threadIdx.x;
    int tok0 = blockIdx.x * 16;
    if (tid < 128) {
        int v = (int)out[OUT_IDX + tok0 * 8 + tid];
        lidx[tid >> 3][tid & 7] = v;
    }
    __syncthreads();
    float4* pb = (float4*)(out + OUT_PROBS) + (size_t)tok0 * 1024;
    for (int it = 0; it < 64; ++it) {
        int i = it * 256 + tid;
        int nl_ = i >> 10, l = (i >> 7) & 7, kg = i & 127;
        int rel = lidx[nl_][l] - kg * 4;
        float4 v;
        v.x = (rel == 0) ? 1.0f : 0.0f;
        v.y = (rel == 1) ? 1.0f : 0.0f;
        v.z = (rel == 2) ? 1.0f : 0.0f;
        v.w = (rel == 3) ? 1.0f : 0.0f;
        pb[i] = v;
    }
}

extern "C" void kernel_launch(void* const* d_in, const int* in_sizes, int n_in,
                              void* d_out, int out_size, void* d_ws, size_t ws_size,
                              hipStream_t stream) {
    const float* z = (const float*)d_in[0];
    const float* w = (const float*)d_in[1];
    float* out = (float*)d_out;

    float* sb = out + (out_size - SCR_FLOATS);
    f16* zh = (f16*)(sb + SF_ZH);
    f16* zl = (f16*)(sb + SF_ZL);
    f16* wh = (f16*)(sb + SF_WH);
    f16* wl = (f16*)(sb + SF_WL);
    float* b32 = (float*)(sb + SF_B32);
    float* g32 = (float*)(sb + SF_G32);
    double* G2 = (double*)(sb + SF_G2D);
    int* idxws = (int*)(sb + SF_IDX);
    int* idxL = (int*)(sb + SF_IDXL);
    float* klacc = (float*)(sb + SF_KL);

    k_prep_z<<<4096, 256, 0, stream>>>(z, zh, zl);
    k_prep_w<<<1024, 256, 0, stream>>>(w, wh, wl);
    k_prep_b<<<16, 256, 0, stream>>>(w, b32);
    k_prep_misc<<<1, 256, 0, stream>>>(g32, G2, out + OUT_LOSS);
    for (int l = 0; l < 8; ++l) {
        k_level<<<512, 256, 0, stream>>>(z, w, zh, zl, wh, wl, g32, G2, b32,
                                         idxws, idxL, klacc, l);
        if (l < 7) {
            k_gsum<<<32, 256, 0, stream>>>(w, idxL, g32, l);
            k_g2<<<8, 256, 0, stream>>>(w, g32, G2, l);
        }
    }
    k_out1<<<256, 256, 0, stream>>>(w, b32, idxws, klacc, out);
    k_out2<<<1024, 256, 0, stream>>>(out);
}

// Round 8
// 1455.120 us; speedup vs baseline: 2.4679x; 1.0433x over previous
//
#include <hip/hip_runtime.h>

// HierarchicalResidualQuantizer on gfx950 — numpy-fp32-exact decision path.
// N=16384 tokens, D=256, L=8 levels, K=512 codes.
// Outputs (flat fp32 in d_out): q_out[16,256,32,32] @0, indices[16,32,32,8] @4194304,
// loss[16] @4325376, all_probs[16384,8,512] @4325392.  Total 71,434,256 floats.
// Scratch lives in the TAIL of the probs region (overwritten last by k_out2).
//
// R8: (1) k_gsum consumer uses a fully-unrolled 2x16-float4 register ping-pong
// (prefetch group s+1 while the sequential chain adds group s) -> chain-latency
// bound. (2) k_g2 fused into k_gsum via last-block-done (release fence +
// device-scope atomic counter; reader uses atomic loads). (3) k_level computes
// each emulated fp32 score ONCE (D stored in-place in acc regs), no fp64 in
// the hot loop. Decision path (Phase E exact numpy-fp32) unchanged.

typedef _Float16 f16;
typedef _Float16 half8 __attribute__((ext_vector_type(8)));
typedef _Float16 half4v __attribute__((ext_vector_type(4)));
typedef float f32x4 __attribute__((ext_vector_type(4)));

#define LOGK 6.238324625039508f

#define OUT_IDX 4194304
#define OUT_LOSS 4325376
#define OUT_PROBS 4325392

#define SCR_FLOATS 5526800
// scratch offsets in floats
#define SF_ZH 0              // f16[16384*256]
#define SF_ZL 2097152        // f16[16384*256]
#define SF_WH 4194304        // f16[4096*256]
#define SF_WL 4718592        // f16[4096*256]
#define SF_B32 5242880       // float[4096]  fp32 pairwise ||w||^2 (numpy-exact)
#define SF_G32 5246976       // float[256]   fp32 global_sum (numpy-exact bits)
#define SF_G2D 5247232       // double[512]  2*g.w_k for next level (approx path)
#define SF_IDX 5248256       // int[16384*8]
#define SF_IDXL 5379328      // int[8*16384] level-major indices
#define SF_KL 5510400        // float[16384]
#define SF_DONE 5526784      // int[1] cross-block counter (+pad)

// ---------- numpy pairwise-128 block: 8 accumulators + fixed combine tree ----------
__device__ __forceinline__ float np_combine8(const float r[8]) {
    return __fadd_rn(__fadd_rn(__fadd_rn(r[0], r[1]), __fadd_rn(r[2], r[3])),
                     __fadd_rn(__fadd_rn(r[4], r[5]), __fadd_rn(r[6], r[7])));
}

__global__ void k_prep_z(const float* __restrict__ z, f16* __restrict__ zh, f16* __restrict__ zl) {
    int i = (blockIdx.x * 256 + threadIdx.x) * 4;
    float4 v = *(const float4*)(z + i);
    half4v h, l;
    float c0 = v.x, c1 = v.y, c2 = v.z, c3 = v.w;
    f16 h0 = (f16)c0, h1 = (f16)c1, h2 = (f16)c2, h3 = (f16)c3;
    h[0] = h0; h[1] = h1; h[2] = h2; h[3] = h3;
    l[0] = (f16)(c0 - (float)h0); l[1] = (f16)(c1 - (float)h1);
    l[2] = (f16)(c2 - (float)h2); l[3] = (f16)(c3 - (float)h3);
    *(half4v*)(zh + i) = h;
    *(half4v*)(zl + i) = l;
}

// fp16 hi/lo split of scaled codebooks (scale 2^(l+4), row norm ~16 at all levels)
__global__ void k_prep_w(const float* __restrict__ w, f16* __restrict__ wh, f16* __restrict__ wl) {
    int row = blockIdx.x * 4 + (threadIdx.x >> 6);
    int lane = threadIdx.x & 63;
    int lvl = row >> 9;
    float sc = (float)(1 << (lvl + 4));
    const float* wr = w + row * 256;
    int d0 = lane * 4;
    float4 v = *(const float4*)(wr + d0);
    half4v h, l;
    float s0 = v.x * sc, s1 = v.y * sc, s2 = v.z * sc, s3 = v.w * sc;
    f16 h0 = (f16)s0, h1 = (f16)s1, h2 = (f16)s2, h3 = (f16)s3;
    h[0] = h0; h[1] = h1; h[2] = h2; h[3] = h3;
    l[0] = (f16)(s0 - (float)h0); l[1] = (f16)(s1 - (float)h1);
    l[2] = (f16)(s2 - (float)h2); l[3] = (f16)(s3 - (float)h3);
    *(half4v*)(wh + row * 256 + d0) = h;
    *(half4v*)(wl + row * 256 + d0) = l;
}

// numpy-exact fp32 (Wl*Wl).sum(-1) for all 4096 rows + misc init (block 0).
__global__ void k_prep_bmisc(const float* __restrict__ w, float* __restrict__ b32,
                             float* __restrict__ g32, double* __restrict__ G2,
                             float* __restrict__ loss_out, int* __restrict__ done) {
    int tid = threadIdx.x;
    int row = blockIdx.x * 256 + tid;   // 0..4095
    const float* wr = w + row * 256;
    float res[2];
    #pragma unroll
    for (int h = 0; h < 2; ++h) {
        const float* x = wr + h * 128;
        float r[8];
        #pragma unroll
        for (int j = 0; j < 8; ++j) r[j] = __fmul_rn(x[j], x[j]);
        for (int i = 8; i < 128; i += 8)
            #pragma unroll
            for (int j = 0; j < 8; ++j) r[j] = __fadd_rn(r[j], __fmul_rn(x[i + j], x[i + j]));
        res[h] = np_combine8(r);
    }
    b32[row] = __fadd_rn(res[0], res[1]);
    if (blockIdx.x == 0) {
        g32[tid] = 0.0f;
        G2[tid] = 0.0; G2[tid + 256] = 0.0;
        if (tid < 16) loss_out[tid] = 0.0f;
        if (tid == 0) *done = 0;
    }
}

// Per-level: MFMA approx scores -> emulated fp32 dist (computed ONCE, stored
// in acc regs) -> candidate pre-filter -> exact numpy-fp32 dist for candidates
// -> argmax (first-max-wins). KL from the emulated dist.
__global__ __launch_bounds__(256) void k_level(
        const float* __restrict__ zf, const float* __restrict__ wf,
        const f16* __restrict__ zh, const f16* __restrict__ zl,
        const f16* __restrict__ wh, const f16* __restrict__ wl,
        const float* __restrict__ g32, const double* __restrict__ G2,
        const float* __restrict__ b32,
        int* __restrict__ idxws, int* __restrict__ idxL,
        float* __restrict__ klacc, int lvl) {
    __shared__ float bS[512];
    __shared__ float g2S[512];
    __shared__ float gS[256];
    __shared__ float pb[32][16];
    __shared__ float aS[32], mgS[32];
    __shared__ float DmaxW[4][32], DmaxS[32];
    __shared__ float seW[4][32], sdW[4][32];
    __shared__ unsigned short cand[32][256];
    __shared__ int ccnt[32];
    __shared__ int bidxS[32];

    const int tid = threadIdx.x;
    const int wave = tid >> 6, lane = tid & 63;
    const int quad = lane >> 4, lr = lane & 15;
    const int tok0 = blockIdx.x * 32;
    const int code0 = wave * 128;

    // stage
    gS[tid] = g32[tid];
    bS[tid] = b32[lvl * 512 + tid]; bS[tid + 256] = b32[lvl * 512 + tid + 256];
    g2S[tid] = (float)G2[tid]; g2S[tid + 256] = (float)G2[tid + 256];
    if (tid < 32) ccnt[tid] = 0;

    // Phase A: MFMA approx (3-term fp16 split, fp32 acc)
    const f16* za = zh + (tok0 + lr) * 256 + quad * 8;
    const f16* zb = zl + (tok0 + lr) * 256 + quad * 8;
    const f16* wa = wh + (lvl * 512 + code0 + lr) * 256 + quad * 8;
    const f16* wb = wl + (lvl * 512 + code0 + lr) * 256 + quad * 8;
    f32x4 acc[2][8];
    #pragma unroll
    for (int mt = 0; mt < 2; ++mt)
        #pragma unroll
        for (int nt = 0; nt < 8; ++nt)
            acc[mt][nt] = (f32x4){0.f, 0.f, 0.f, 0.f};
    for (int k0 = 0; k0 < 256; k0 += 32) {
        half8 ah0 = *(const half8*)(za + k0);
        half8 ah1 = *(const half8*)(za + 16 * 256 + k0);
        half8 al0 = *(const half8*)(zb + k0);
        half8 al1 = *(const half8*)(zb + 16 * 256 + k0);
        half8 bh[8], bl[8];
        #pragma unroll
        for (int nt = 0; nt < 8; ++nt) {
            bh[nt] = *(const half8*)(wa + nt * 16 * 256 + k0);
            bl[nt] = *(const half8*)(wb + nt * 16 * 256 + k0);
        }
        #pragma unroll
        for (int nt = 0; nt < 8; ++nt) {
            acc[0][nt] = __builtin_amdgcn_mfma_f32_16x16x32_f16(ah0, bh[nt], acc[0][nt], 0, 0, 0);
            acc[1][nt] = __builtin_amdgcn_mfma_f32_16x16x32_f16(ah1, bh[nt], acc[1][nt], 0, 0, 0);
            acc[0][nt] = __builtin_amdgcn_mfma_f32_16x16x32_f16(ah0, bl[nt], acc[0][nt], 0, 0, 0);
            acc[1][nt] = __builtin_amdgcn_mfma_f32_16x16x32_f16(ah1, bl[nt], acc[1][nt], 0, 0, 0);
            acc[0][nt] = __builtin_amdgcn_mfma_f32_16x16x32_f16(al0, bh[nt], acc[0][nt], 0, 0, 0);
            acc[1][nt] = __builtin_amdgcn_mfma_f32_16x16x32_f16(al1, bh[nt], acc[1][nt], 0, 0, 0);
        }
    }
    __syncthreads();

    // Phase B: a_n = numpy-pairwise fp32 sum of resid^2 (8 threads/token)
    {
        int t = tid >> 3, s = tid & 7;
        const float* zr = zf + (tok0 + t) * 256;
        #pragma unroll
        for (int h = 0; h < 2; ++h) {
            int base = h * 128 + s;
            float x0 = __fsub_rn(zr[base], gS[base]);
            float r = __fmul_rn(x0, x0);
            for (int i = 1; i < 16; ++i) {
                float xv = __fsub_rn(zr[base + i * 8], gS[base + i * 8]);
                r = __fadd_rn(r, __fmul_rn(xv, xv));
            }
            pb[t][h * 8 + s] = r;
        }
    }
    __syncthreads();
    if (tid < 32) {
        float r0[8], r1[8];
        #pragma unroll
        for (int j = 0; j < 8; ++j) { r0[j] = pb[tid][j]; r1[j] = pb[tid][8 + j]; }
        float a = __fadd_rn(np_combine8(r0), np_combine8(r1));
        aS[tid] = a;
        unsigned e = (__float_as_uint(a) >> 23) & 0xffu;
        float ulp = __uint_as_float((e - 23u) << 23);
        mgS[tid] = 2.5f * ulp + 1e-4f * sqrtf(a) / (float)(1 << lvl) + 1e-6f;
    }
    __syncthreads();

    // Phase C: emulated fp32 dist computed ONCE, stored in-place in acc;
    // per-wave per-token max.
    const float inv2f = 1.0f / (float)(1 << (lvl + 3));
    float b8[8], g28[8];
    #pragma unroll
    for (int nt = 0; nt < 8; ++nt) {
        b8[nt] = bS[code0 + nt * 16 + lr];
        g28[nt] = g2S[code0 + nt * 16 + lr];
    }
    #pragma unroll
    for (int mt = 0; mt < 2; ++mt) {
        #pragma unroll
        for (int r = 0; r < 4; ++r) {
            int tl = mt * 16 + quad * 4 + r;
            float a = aS[tl];
            float m = -3.4e38f;
            #pragma unroll
            for (int nt = 0; nt < 8; ++nt) {
                float c2 = __fsub_rn(__fmul_rn(acc[mt][nt][r], inv2f), g28[nt]);
                float D = -__fsub_rn(__fadd_rn(a, b8[nt]), c2);
                acc[mt][nt][r] = D;
                m = fmaxf(m, D);
            }
            #pragma unroll
            for (int msk = 1; msk < 16; msk <<= 1) m = fmaxf(m, __shfl_xor(m, msk));
            if (lr == 0) DmaxW[wave][tl] = m;
        }
    }
    __syncthreads();
    if (tid < 32)
        DmaxS[tid] = fmaxf(fmaxf(DmaxW[0][tid], DmaxW[1][tid]),
                           fmaxf(DmaxW[2][tid], DmaxW[3][tid]));
    __syncthreads();

    // Phase C2: softmax stats + candidate collection (reads D from regs)
    #pragma unroll
    for (int mt = 0; mt < 2; ++mt) {
        #pragma unroll
        for (int r = 0; r < 4; ++r) {
            int tl = mt * 16 + quad * 4 + r;
            float Dm = DmaxS[tl], mg = mgS[tl];
            float se = 0.f, sd = 0.f;
            #pragma unroll
            for (int nt = 0; nt < 8; ++nt) {
                float D = acc[mt][nt][r];
                float d = Dm - D;
                se += __expf(-d);
                sd += d;
                if (D >= Dm - mg) {
                    int pos = atomicAdd(&ccnt[tl], 1);
                    if (pos < 256) cand[tl][pos] = (unsigned short)(code0 + nt * 16 + lr);
                }
            }
            #pragma unroll
            for (int msk = 1; msk < 16; msk <<= 1) {
                se += __shfl_xor(se, msk);
                sd += __shfl_xor(sd, msk);
            }
            if (lr == 0) { seW[wave][tl] = se; sdW[wave][tl] = sd; }
        }
    }
    __syncthreads();

    if (tid < 32) {
        float se = seW[0][tid] + seW[1][tid] + seW[2][tid] + seW[3][tid];
        float sd = sdW[0][tid] + sdW[1][tid] + sdW[2][tid] + sdW[3][tid];
        float kl = __logf(se) + sd * (1.0f / 512.0f) - LOGK;
        int n = tok0 + tid;
        float prev = (lvl == 0) ? 0.0f : klacc[n];
        klacc[n] = prev + 0.1f * kl;
    }

    // Phase E: exact numpy-fp32 dist for candidates (sequential-FMA c)
    {
        int t = tid >> 3, s = tid & 7;
        int n = tok0 + t;
        const float* zr = zf + n * 256;
        int cnt = ccnt[t]; if (cnt > 256) cnt = 256;
        float aT = aS[t];
        float bD = -3.4e38f; int bI = 0x7fffffff;
        for (int ci = s; ci < cnt; ci += 8) {
            int code = cand[t][ci];
            const float* wr = wf + (lvl * 512 + code) * 256;
            float c = 0.f;
            #pragma unroll 8
            for (int j = 0; j < 256; ++j)
                c = fmaf(__fsub_rn(zr[j], gS[j]), wr[j], c);
            float D = -__fsub_rn(__fadd_rn(aT, bS[code]), __fadd_rn(c, c));
            if (D > bD || (D == bD && code < bI)) { bD = D; bI = code; }
        }
        #pragma unroll
        for (int msk = 1; msk < 8; msk <<= 1) {
            float oD = __shfl_xor(bD, msk);
            int oI = __shfl_xor(bI, msk);
            if (oD > bD || (oD == bD && oI < bI)) { bD = oD; bI = oI; }
        }
        if (s == 0) bidxS[t] = bI;
    }
    __syncthreads();
    if (tid < 32) {
        int gi = bidxS[tid];
        int n = tok0 + tid;
        idxws[n * 8 + lvl] = gi;
        idxL[lvl * 16384 + n] = gi;
    }
}

// numpy-exact g update v5 + fused G2. 32 blocks x 8 dims.
// Producers (192 thr) gather chunk ch+1 into vals[buf][dim][tok] while the
// 8 consumer lanes run the sequential fp32 chain over chunk ch via a fully
// unrolled 2x16-float4 register ping-pong (prefetch group s+1 during adds of
// group s; compile-time LDS offsets). Order bit-identical to validated R4.
// Last block (device-fenced atomic counter) recomputes G2 for level lvl+1.
__global__ __launch_bounds__(256) void k_gsum(const float* __restrict__ w,
        const int* __restrict__ idxL, float* __restrict__ g32,
        double* __restrict__ G2, int* __restrict__ done, int lvl) {
    __shared__ float wcol[512 * 13];       // [code][dim(8), stride 13]
    __shared__ float vals[2][8][520];      // [buf][dim][token-in-chunk]
    __shared__ int islast;
    __shared__ float gf[256];
    const int tid = threadIdx.x;
    const int d0 = blockIdx.x * 8;
    {   // stage the 512x8 column slice
        const float* wb = w + lvl * 131072 + d0;
        for (int i = tid; i < 4096; i += 256)
            wcol[(i >> 3) * 13 + (i & 7)] = wb[(i >> 3) * 256 + (i & 7)];
    }
    const int* __restrict__ codes = idxL + lvl * 16384;
    const bool producer = (tid < 192);
    const int cl = tid - 248;              // consumer lane 0..7 when >= 0
    if (producer) {
        for (int k = tid; k < 512; k += 192) {
            int c = codes[k] * 13;
            float v0 = wcol[c], v1 = wcol[c + 1], v2 = wcol[c + 2], v3 = wcol[c + 3];
            float v4 = wcol[c + 4], v5 = wcol[c + 5], v6 = wcol[c + 6], v7 = wcol[c + 7];
            vals[0][0][k] = v0; vals[0][1][k] = v1; vals[0][2][k] = v2; vals[0][3][k] = v3;
            vals[0][4][k] = v4; vals[0][5][k] = v5; vals[0][6][k] = v6; vals[0][7][k] = v7;
        }
    }
    __syncthreads();
    float acc = 0.f;
    for (int ch = 0; ch < 32; ++ch) {
        const int cb = ch & 1, nb = cb ^ 1;
        if (producer) {
            if (ch < 31) {
                int base = (ch + 1) << 9;
                for (int k = tid; k < 512; k += 192) {
                    int c = codes[base + k] * 13;
                    float v0 = wcol[c], v1 = wcol[c + 1], v2 = wcol[c + 2], v3 = wcol[c + 3];
                    float v4 = wcol[c + 4], v5 = wcol[c + 5], v6 = wcol[c + 6], v7 = wcol[c + 7];
                    vals[nb][0][k] = v0; vals[nb][1][k] = v1; vals[nb][2][k] = v2; vals[nb][3][k] = v3;
                    vals[nb][4][k] = v4; vals[nb][5][k] = v5; vals[nb][6][k] = v6; vals[nb][7][k] = v7;
                }
            }
        } else if (cl >= 0) {
            const float4* vp = (const float4*)(&vals[cb][cl][0]);  // 128 float4
            float4 A[16], B[16];
            #pragma unroll
            for (int j = 0; j < 16; ++j) A[j] = vp[j];
            #pragma unroll
            for (int s = 0; s < 8; ++s) {
                if ((s & 1) == 0) {
                    if (s < 7) {
                        #pragma unroll
                        for (int j = 0; j < 16; ++j) B[j] = vp[(s + 1) * 16 + j];
                    }
                    #pragma unroll
                    for (int j = 0; j < 16; ++j) {
                        acc = __fadd_rn(acc, A[j].x);
                        acc = __fadd_rn(acc, A[j].y);
                        acc = __fadd_rn(acc, A[j].z);
                        acc = __fadd_rn(acc, A[j].w);
                    }
                } else {
                    if (s < 7) {
                        #pragma unroll
                        for (int j = 0; j < 16; ++j) A[j] = vp[(s + 1) * 16 + j];
                    }
                    #pragma unroll
                    for (int j = 0; j < 16; ++j) {
                        acc = __fadd_rn(acc, B[j].x);
                        acc = __fadd_rn(acc, B[j].y);
                        acc = __fadd_rn(acc, B[j].z);
                        acc = __fadd_rn(acc, B[j].w);
                    }
                }
            }
        }
        __syncthreads();
    }
    if (cl >= 0) g32[d0 + cl] = __fadd_rn(g32[d0 + cl], acc);
    __threadfence();           // release: own stores visible at device scope
    __syncthreads();
    if (tid == 0) {
        int prev = atomicAdd(done, 1);
        islast = (prev == 31) ? 1 : 0;
    }
    __syncthreads();
    if (islast) {
        if (tid == 0) *done = 0;           // reset for next level
        __threadfence();                   // acquire side
        // device-coherent read of the full g vector
        gf[tid] = atomicAdd(&g32[tid], 0.0f);
        __syncthreads();
        const float* wn = w + (lvl + 1) * 131072;
        for (int k = tid; k < 512; k += 256) {
            const float* wr = wn + k * 256;
            double s = 0.0;
            for (int j = 0; j < 256; ++j) s = fma((double)gf[j], (double)wr[j], s);
            G2[k] = 2.0 * s;
        }
    }
}

// Epilogue 1: q_out (transposed), indices (as float), per-image loss.
__global__ __launch_bounds__(256) void k_out1(const float* __restrict__ w,
        const float* __restrict__ b32, const int* __restrict__ idxws,
        const float* __restrict__ klacc, float* __restrict__ out) {
    __shared__ int lidx[64][8];
    int tid = threadIdx.x;
    int tok0 = blockIdx.x * 64;
    int b = tok0 >> 10, hw0 = tok0 & 1023;

    for (int s = tid; s < 512; s += 256) {
        int v = idxws[tok0 * 8 + s];
        lidx[s >> 3][s & 7] = v;
        out[OUT_IDX + tok0 * 8 + s] = (float)v;
    }
    __syncthreads();

    {
        int j = tid & 63, q = tid >> 6;
        int id[8];
        #pragma unroll
        for (int l = 0; l < 8; ++l) id[l] = lidx[j][l];
        for (int dd = 0; dd < 64; ++dd) {
            int d = q * 64 + dd;
            float s = 0.f;
            #pragma unroll
            for (int l = 0; l < 8; ++l) s += w[l * 131072 + id[l] * 256 + d];
            out[b * 262144 + d * 1024 + hw0 + j] = s;
        }
    }

    if (tid < 64) {
        int n = tok0 + tid;
        float lv = klacc[n];
        float nl = 0.f;
        #pragma unroll
        for (int jj = 0; jj < 7; ++jj) {
            float up = sqrtf(b32[jj * 512 + lidx[tid][jj]]);
            float lo = sqrtf(b32[(jj + 1) * 512 + lidx[tid][jj + 1]]);
            float ratio = 4.0f * (lo / up);
            float m = fmaxf(ratio, 1.0f) - 1.0f;
            nl += m * m;
        }
        lv += nl * (1.0f / 7.0f) * 0.1f;
        #pragma unroll
        for (int msk = 1; msk < 64; msk <<= 1) lv += __shfl_xor(lv, msk);
        if (tid == 0) atomicAdd(out + OUT_LOSS + b, lv * (1.0f / 1024.0f));
    }
}

// Epilogue 2: fill the ENTIRE probs region (one-hot), overwriting scratch tail.
__global__ __launch_bounds__(256) void k_out2(float* __restrict__ out) {
    __shared__ int lidx[16][8];
    int tid = threadIdx.x;
    int tok0 = blockIdx.x * 16;
    if (tid < 128) {
        int v = (int)out[OUT_IDX + tok0 * 8 + tid];
        lidx[tid >> 3][tid & 7] = v;
    }
    __syncthreads();
    float4* pb = (float4*)(out + OUT_PROBS) + (size_t)tok0 * 1024;
    for (int it = 0; it < 64; ++it) {
        int i = it * 256 + tid;
        int nl_ = i >> 10, l = (i >> 7) & 7, kg = i & 127;
        int rel = lidx[nl_][l] - kg * 4;
        float4 v;
        v.x = (rel == 0) ? 1.0f : 0.0f;
        v.y = (rel == 1) ? 1.0f : 0.0f;
        v.z = (rel == 2) ? 1.0f : 0.0f;
        v.w = (rel == 3) ? 1.0f : 0.0f;
        pb[i] = v;
    }
}

extern "C" void kernel_launch(void* const* d_in, const int* in_sizes, int n_in,
                              void* d_out, int out_size, void* d_ws, size_t ws_size,
                              hipStream_t stream) {
    const float* z = (const float*)d_in[0];
    const float* w = (const float*)d_in[1];
    float* out = (float*)d_out;

    float* sb = out + (out_size - SCR_FLOATS);
    f16* zh = (f16*)(sb + SF_ZH);
    f16* zl = (f16*)(sb + SF_ZL);
    f16* wh = (f16*)(sb + SF_WH);
    f16* wl = (f16*)(sb + SF_WL);
    float* b32 = (float*)(sb + SF_B32);
    float* g32 = (float*)(sb + SF_G32);
    double* G2 = (double*)(sb + SF_G2D);
    int* idxws = (int*)(sb + SF_IDX);
    int* idxL = (int*)(sb + SF_IDXL);
    float* klacc = (float*)(sb + SF_KL);
    int* done = (int*)(sb + SF_DONE);

    k_prep_z<<<4096, 256, 0, stream>>>(z, zh, zl);
    k_prep_w<<<1024, 256, 0, stream>>>(w, wh, wl);
    k_prep_bmisc<<<16, 256, 0, stream>>>(w, b32, g32, G2, out + OUT_LOSS, done);
    for (int l = 0; l < 8; ++l) {
        k_level<<<512, 256, 0, stream>>>(z, w, zh, zl, wh, wl, g32, G2, b32,
                                         idxws, idxL, klacc, l);
        if (l < 7)
            k_gsum<<<32, 256, 0, stream>>>(w, idxL, g32, G2, done, l);
    }
    k_out1<<<256, 256, 0, stream>>>(w, b32, idxws, klacc, out);
    k_out2<<<1024, 256, 0, stream>>>(out);
}